// Round 7
// baseline (1048.018 us; speedup 1.0000x reference)
//
#include <hip/hip_runtime.h>
#include <math.h>

// ---------------------------------------------------------------------------
// MambaPredictor forward. R6: parallel scan correction, fused dt, batched
// scale-mambas, single-kernel tail, merged weight conversion.
// B=4 L=1024 NF=64 DM=256 DS=16 SCS=8 NL=4 DI=512 DTR=16 DC=4 NFM=6 NH=4
// ---------------------------------------------------------------------------

typedef short short8v __attribute__((ext_vector_type(8)));
typedef float f32x4   __attribute__((ext_vector_type(4)));

__device__ __forceinline__ float geluf(float x){ return 0.5f*x*(1.0f + erff(x*0.70710678118654752f)); }
__device__ __forceinline__ float softplusf_(float x){ return (x > 20.f) ? x : log1pf(expf(x)); }
__device__ __forceinline__ unsigned short f2bf(float f){
  unsigned int u = __float_as_uint(f);
  unsigned int r = (u + 0x7FFFu + ((u >> 16) & 1u)) >> 16;
  return (unsigned short)r;
}

// ---------------- merged fp32 -> bf16 weight convert (6 segments) ----------
__global__ __launch_bounds__(256) void k_f2b_all(
    const float* s0, unsigned short* d0,   // 1024 blocks
    const float* s1, unsigned short* d1,   // 512
    const float* s2, unsigned short* d2,   // 96
    const float* s3, unsigned short* d3,   // 768
    const float* s4, unsigned short* d4,   // 384
    const float* s5, unsigned short* d5)   // 48
{
  int blk = blockIdx.x;
  const float* s; unsigned short* d; int base;
  if      (blk < 1024){ s=s0; d=d0; base=0; }
  else if (blk < 1536){ s=s1; d=d1; base=1024; }
  else if (blk < 1632){ s=s2; d=d2; base=1536; }
  else if (blk < 2400){ s=s3; d=d3; base=1632; }
  else if (blk < 2784){ s=s4; d=d4; base=2400; }
  else                { s=s5; d=d5; base=2784; }
  int i = ((blk - base)*256 + threadIdx.x)*4;
  float4 v = *(const float4*)(s + i);
  *(ushort4*)(d + i) = make_ushort4(f2bf(v.x), f2bf(v.y), f2bf(v.z), f2bf(v.w));
}

// ---------------- initial: h = gelu(LN(x @ in_w^T + in_b)) -----------------
__global__ __launch_bounds__(256) void k_inproj(
    const float* __restrict__ x, const float* __restrict__ w,
    const float* __restrict__ b, const float* __restrict__ g,
    const float* __restrict__ beta, float* __restrict__ h)
{
  __shared__ float xr[64];
  __shared__ float r1[4], r2[4];
  int row = blockIdx.x;
  int tid = threadIdx.x;
  if (tid < 64) xr[tid] = x[row*64 + tid];
  __syncthreads();
  float acc = b[tid];
  const float* wr = w + tid*64;
  #pragma unroll
  for (int k = 0; k < 64; k++) acc += xr[k]*wr[k];
  float s1 = acc, s2 = acc*acc;
  #pragma unroll
  for (int o = 32; o > 0; o >>= 1){ s1 += __shfl_down(s1,o,64); s2 += __shfl_down(s2,o,64); }
  if ((tid & 63) == 0){ r1[tid>>6] = s1; r2[tid>>6] = s2; }
  __syncthreads();
  float S1 = r1[0]+r1[1]+r1[2]+r1[3];
  float S2 = r2[0]+r2[1]+r2[2]+r2[3];
  float m = S1*(1.f/256.f);
  float var = S2*(1.f/256.f) - m*m;
  float xn = (acc - m)*rsqrtf(var + 1e-5f)*g[tid] + beta[tid];
  h[row*256 + tid] = geluf(xn);
}

// ---------------- LayerNorm over 256 -> bf16 (main layers, row = blockIdx) -
__global__ __launch_bounds__(256) void k_ln(
    const float* __restrict__ src, const float* __restrict__ g, const float* __restrict__ beta,
    unsigned short* __restrict__ dst)
{
  __shared__ float r1[4], r2[4];
  int r = blockIdx.x, tid = threadIdx.x;
  float v = src[r*256 + tid];
  float s1 = v, s2 = v*v;
  #pragma unroll
  for (int o = 32; o > 0; o >>= 1){ s1 += __shfl_down(s1,o,64); s2 += __shfl_down(s2,o,64); }
  if ((tid & 63) == 0){ r1[tid>>6] = s1; r2[tid>>6] = s2; }
  __syncthreads();
  float S1 = r1[0]+r1[1]+r1[2]+r1[3];
  float S2 = r2[0]+r2[1]+r2[2]+r2[3];
  float m = S1*(1.f/256.f);
  float var = S2*(1.f/256.f) - m*m;
  dst[r*256 + tid] = f2bf((v - m)*rsqrtf(var + 1e-5f)*g[tid] + beta[tid]);
}

// ---------------- LayerNorm for batched scale regions ----------------------
// regions: z0 rows [0,64) uses 20, z1 [64,192) uses 80, z2 [192,448) uses 200
__device__ __forceinline__ void sc_region(int r, int& z, int& roff, int& s){
  if (r < 64){ z=0; roff=0; s=5; }
  else if (r < 192){ z=1; roff=64; s=20; }
  else { z=2; roff=192; s=50; }
}

__global__ __launch_bounds__(256) void k_ln_sc(
    const float* __restrict__ h, const float* __restrict__ gb, const float* __restrict__ bb,
    unsigned short* __restrict__ dst)
{
  __shared__ float r1[4], r2[4];
  int r = blockIdx.x, tid = threadIdx.x;
  int z, roff, s; sc_region(r, z, roff, s);
  int local = r - roff;
  if (local >= 4*s) return;
  int b = local / s, t = local % s;
  float v = h[(b*1024 + (1024 - s) + t)*256 + tid];
  const float* g = gb + z*256; const float* be = bb + z*256;
  float s1 = v, s2 = v*v;
  #pragma unroll
  for (int o = 32; o > 0; o >>= 1){ s1 += __shfl_down(s1,o,64); s2 += __shfl_down(s2,o,64); }
  if ((tid & 63) == 0){ r1[tid>>6] = s1; r2[tid>>6] = s2; }
  __syncthreads();
  float S1 = r1[0]+r1[1]+r1[2]+r1[3];
  float S2 = r2[0]+r2[1]+r2[2]+r2[3];
  float m = S1*(1.f/256.f);
  float var = S2*(1.f/256.f) - m*m;
  dst[r*256 + tid] = f2bf((v - m)*rsqrtf(var + 1e-5f)*g[tid] + be[tid]);
}

// ---------------- MFMA GEMM: C = A(M,K)bf16 @ W(N,K)bf16^T, fp32 acc -------
// MODE 0: store. MODE 1: +resid (main out-proj, in-place h). MODE 2: pool.
// SCB: scale-batched (weight/z per 64-row tile, padded regions).
template<int MODE, int SCB>
__global__ __launch_bounds__(256) void k_mm64(
    const unsigned short* __restrict__ A, const unsigned short* __restrict__ Wb,
    float* __restrict__ C,
    const float* __restrict__ resid,
    float* __restrict__ pool_out,
    int M, int N, int K, int wstr)
{
  int tid = threadIdx.x;
  int wave = tid >> 6, lane = tid & 63;
  int mh = wave & 1, nh = wave >> 1;
  int m0 = blockIdx.y*64 + mh*32;
  int n0 = blockIdx.x*64 + nh*32;
  int z = 0, roff = 0, sc = 0;
  const unsigned short* W = Wb;
  if (SCB){ sc_region(blockIdx.y*64, z, roff, sc); W += z*wstr; }
  int lrow = lane & 15, kc = lane >> 4;
  f32x4 acc[2][2] = {{{0.f,0.f,0.f,0.f},{0.f,0.f,0.f,0.f}},{{0.f,0.f,0.f,0.f},{0.f,0.f,0.f,0.f}}};
  for (int k0 = 0; k0 < K; k0 += 32){
    short8v a[2], b[2];
    #pragma unroll
    for (int mi = 0; mi < 2; mi++){
      int r = m0 + mi*16 + lrow; r = min(r, M-1);
      a[mi] = *(const short8v*)(A + r*K + k0 + kc*8);
    }
    #pragma unroll
    for (int ni = 0; ni < 2; ni++){
      int c = n0 + ni*16 + lrow;
      b[ni] = *(const short8v*)(W + c*K + k0 + kc*8);
    }
    #pragma unroll
    for (int mi = 0; mi < 2; mi++)
      #pragma unroll
      for (int ni = 0; ni < 2; ni++)
        acc[mi][ni] = __builtin_amdgcn_mfma_f32_16x16x32_bf16(a[mi], b[ni], acc[mi][ni], 0, 0, 0);
  }
  int rb = kc*4;
  #pragma unroll
  for (int mi = 0; mi < 2; mi++){
    #pragma unroll
    for (int rr = 0; rr < 4; rr++){
      int grow = m0 + mi*16 + rb + rr;
      if (grow >= M) continue;
      #pragma unroll
      for (int ni = 0; ni < 2; ni++){
        int gcol = n0 + ni*16 + lrow;
        float v = acc[mi][ni][rr];
        if (MODE == 0){
          C[grow*N + gcol] = v;
        } else if (MODE == 1){
          // main out-proj: row = b*1024 + t, resid/dst same layout
          C[grow*N + gcol] = resid[grow*256 + gcol] + v;
        } else {
          // scale pool: skip pad rows, atomic mean-accumulate
          int local = grow - roff;
          if (local < 4*sc){
            int bb2 = local / sc, t = local % sc;
            float rv = resid[(bb2*1024 + (1024 - sc) + t)*256 + gcol] + v;
            atomicAdd(&pool_out[bb2*768 + z*256 + gcol], rv*(1.f/(float)sc));
          }
        }
      }
    }
  }
}

// ---- xp GEMM (narrow) + fused dt: xd = uc@xpw^T ; dt = softplus(xd[:16]@dtw^T+dtb)
template<int NT>
__global__ __launch_bounds__(256) void k_mmNdt(
    const unsigned short* __restrict__ A, const unsigned short* __restrict__ W,
    float* __restrict__ Cout,
    const float* __restrict__ dtw, const float* __restrict__ dtb,
    float* __restrict__ dtout, int M, int K)
{
  __shared__ float sxd[64][16];
  int tid = threadIdx.x;
  int wave = tid >> 6, lane = tid & 63;
  int bm0 = blockIdx.y*64;
  int m0 = bm0 + wave*16;
  int lrow = lane & 15, kc = lane >> 4;
  f32x4 acc[NT];
  #pragma unroll
  for (int ni = 0; ni < NT; ni++) acc[ni] = (f32x4){0.f,0.f,0.f,0.f};
  for (int k0 = 0; k0 < K; k0 += 32){
    int r = m0 + lrow; r = min(r, M-1);
    short8v a = *(const short8v*)(A + r*K + k0 + kc*8);
    #pragma unroll
    for (int ni = 0; ni < NT; ni++){
      short8v b = *(const short8v*)(W + (ni*16 + lrow)*K + k0 + kc*8);
      acc[ni] = __builtin_amdgcn_mfma_f32_16x16x32_bf16(a, b, acc[ni], 0, 0, 0);
    }
  }
  int rb = kc*4;
  #pragma unroll
  for (int rr = 0; rr < 4; rr++){
    int grow = m0 + rb + rr;
    #pragma unroll
    for (int ni = 0; ni < NT; ni++)
      Cout[grow*(NT*16) + ni*16 + lrow] = acc[ni][rr];
    sxd[wave*16 + rb + rr][lrow] = acc[0][rr];
  }
  __syncthreads();
  // dt part: thread handles d0=tid, d1=tid+256 for the block's 64 rows
  int d0 = tid, d1 = tid + 256;
  float w0[16], w1[16];
  #pragma unroll
  for (int j = 0; j < 16; j++){ w0[j] = dtw[d0*16 + j]; w1[j] = dtw[d1*16 + j]; }
  float b0 = dtb[d0], b1 = dtb[d1];
  for (int r = 0; r < 64; r++){
    float a0 = b0, a1 = b1;
    #pragma unroll
    for (int j = 0; j < 16; j++){
      float xv = sxd[r][j];
      a0 = fmaf(xv, w0[j], a0);
      a1 = fmaf(xv, w1[j], a1);
    }
    dtout[(bm0 + r)*512 + d0] = softplusf_(a0);
    dtout[(bm0 + r)*512 + d1] = softplusf_(a1);
  }
}

// scale-batched variant (NT=2, weight select by tile)
__global__ __launch_bounds__(256) void k_mmNdt_sc(
    const unsigned short* __restrict__ A, const unsigned short* __restrict__ Wb,
    float* __restrict__ Cout,
    const float* __restrict__ dtwb, const float* __restrict__ dtbb,
    float* __restrict__ dtout, int M, int K)
{
  __shared__ float sxd[64][16];
  int tid = threadIdx.x;
  int wave = tid >> 6, lane = tid & 63;
  int bm0 = blockIdx.y*64;
  int z, roff, s; sc_region(bm0, z, roff, s);
  const unsigned short* W = Wb + z*16384;
  const float* dtw = dtwb + z*8192;
  const float* dtb = dtbb + z*512;
  int m0 = bm0 + wave*16;
  int lrow = lane & 15, kc = lane >> 4;
  f32x4 acc[2];
  acc[0] = (f32x4){0.f,0.f,0.f,0.f}; acc[1] = (f32x4){0.f,0.f,0.f,0.f};
  for (int k0 = 0; k0 < K; k0 += 32){
    int r = m0 + lrow; r = min(r, M-1);
    short8v a = *(const short8v*)(A + r*K + k0 + kc*8);
    #pragma unroll
    for (int ni = 0; ni < 2; ni++){
      short8v b = *(const short8v*)(W + (ni*16 + lrow)*K + k0 + kc*8);
      acc[ni] = __builtin_amdgcn_mfma_f32_16x16x32_bf16(a, b, acc[ni], 0, 0, 0);
    }
  }
  int rb = kc*4;
  #pragma unroll
  for (int rr = 0; rr < 4; rr++){
    int grow = m0 + rb + rr;
    #pragma unroll
    for (int ni = 0; ni < 2; ni++)
      Cout[grow*32 + ni*16 + lrow] = acc[ni][rr];
    sxd[wave*16 + rb + rr][lrow] = acc[0][rr];
  }
  __syncthreads();
  int d0 = tid, d1 = tid + 256;
  float w0[16], w1[16];
  #pragma unroll
  for (int j = 0; j < 16; j++){ w0[j] = dtw[d0*16 + j]; w1[j] = dtw[d1*16 + j]; }
  float b0 = dtb[d0], b1 = dtb[d1];
  for (int r = 0; r < 64; r++){
    float a0 = b0, a1 = b1;
    #pragma unroll
    for (int j = 0; j < 16; j++){
      float xv = sxd[r][j];
      a0 = fmaf(xv, w0[j], a0);
      a1 = fmaf(xv, w1[j], a1);
    }
    dtout[(bm0 + r)*512 + d0] = softplusf_(a0);
    dtout[(bm0 + r)*512 + d1] = softplusf_(a1);
  }
}

// ---------------- depthwise causal conv (DC=4) + SiLU (main, L=1024) -------
__global__ __launch_bounds__(256) void k_conv(
    const float* __restrict__ uz, const float* __restrict__ cw, const float* __restrict__ cb,
    float* __restrict__ uc, unsigned short* __restrict__ ucb)
{
  int row = blockIdx.x;
  int t = row & 1023;
  int tid = threadIdx.x;
  for (int d = tid; d < 512; d += 256){
    float acc = cb[d];
    const float* w = cw + d*4;
    #pragma unroll
    for (int k = 0; k < 4; k++){
      int ts = t - 3 + k;
      if (ts >= 0) acc += uz[(row - (3-k))*1024 + d]*w[k];
    }
    float s = acc/(1.f + expf(-acc));
    uc[row*512 + d] = s;
    ucb[row*512 + d] = f2bf(s);
  }
}

// scale-batched conv
__global__ __launch_bounds__(256) void k_conv_sc(
    const float* __restrict__ uz, const float* __restrict__ cwb, const float* __restrict__ cbb,
    float* __restrict__ uc, unsigned short* __restrict__ ucb)
{
  int row = blockIdx.x;
  int z, roff, s; sc_region(row, z, roff, s);
  int local = row - roff;
  if (local >= 4*s) return;
  int t = local % s;
  const float* cw = cwb + z*2048;
  const float* cb = cbb + z*512;
  int tid = threadIdx.x;
  for (int d = tid; d < 512; d += 256){
    float acc = cb[d];
    const float* w = cw + d*4;
    #pragma unroll
    for (int k = 0; k < 4; k++){
      int ts = t - 3 + k;
      if (ts >= 0) acc += uz[(row - (3-k))*1024 + d]*w[k];
    }
    float sv = acc/(1.f + expf(-acc));
    uc[row*512 + d] = sv;
    ucb[row*512 + d] = f2bf(sv);
  }
}

// ============ chunked selective scan: p1 (serial local) + p2 + parallel corr
// p1: local scan per 64-chunk with h0=0; stores y_local, Scum (incl.), hend, sum-dt
__global__ __launch_bounds__(64) void k_scan_p1y(
    const float* __restrict__ dt, const float* __restrict__ uc,
    const float* __restrict__ xd, const float* __restrict__ Alog,
    float* __restrict__ hend, float* __restrict__ sdtb,
    float* __restrict__ yloc, float* __restrict__ Scum)
{
  const int CL = 64, NCH = 16;
  __shared__ float sdt[64][64], suc[64][64];
  __shared__ float sBC[64][32];
  int tid = threadIdx.x;
  int dblk = blockIdx.x;
  int d = dblk*64 + tid;
  int b = blockIdx.y, ch = blockIdx.z;
  int t0 = ch*CL;
  float A[16];
  #pragma unroll
  for (int n = 0; n < 16; n++) A[n] = -__expf(Alog[d*16 + n]);
  for (int e = tid; e < CL*16; e += 64){
    int t = e >> 4, q = (e & 15)*4;
    long off = (long)(b*1024 + t0 + t)*512 + dblk*64 + q;
    *(float4*)&sdt[t][q] = *(const float4*)(dt + off);
    *(float4*)&suc[t][q] = *(const float4*)(uc + off);
  }
  for (int e = tid; e < CL*8; e += 64){
    int t = e >> 3, q = (e & 7)*4;
    *(float4*)&sBC[t][q] = *(const float4*)(xd + (long)(b*1024 + t0 + t)*48 + 16 + q);
  }
  __syncthreads();
  float h[16];
  #pragma unroll
  for (int n = 0; n < 16; n++) h[n] = 0.f;
  float Ss = 0.f;
  #pragma unroll 2
  for (int t = 0; t < CL; t++){
    float dtv = sdt[t][tid];
    float uv  = suc[t][tid];
    Ss += dtv;
    float du = dtv*uv;
    float y = 0.f;
    #pragma unroll
    for (int n = 0; n < 16; n++){
      h[n] = fmaf(__expf(dtv*A[n]), h[n], du*sBC[t][n]);
      y = fmaf(h[n], sBC[t][16+n], y);
    }
    long row = (long)(b*1024 + t0 + t);
    yloc[row*512 + d] = y;
    Scum[row*512 + d] = Ss;
  }
  int base = ((b*NCH + ch)*512 + d)*16;
  #pragma unroll
  for (int q = 0; q < 4; q++)
    *(float4*)(hend + base + q*4) = make_float4(h[q*4], h[q*4+1], h[q*4+2], h[q*4+3]);
  sdtb[(b*NCH + ch)*512 + d] = Ss;
}

// p2: sequential combine over 16 chunks; also emits Aneg table (b==0 threads)
__global__ __launch_bounds__(256) void k_scomb(
    const float* __restrict__ hend, const float* __restrict__ sdtb,
    const float* __restrict__ Alog, float* __restrict__ hstart,
    float* __restrict__ Aneg)
{
  const int NCH = 16;
  int idx = blockIdx.x*256 + threadIdx.x;
  int low = idx & 8191;
  int d = (idx >> 4) & 511, b = idx >> 13;
  float A = -__expf(Alog[low]);
  if (b == 0) Aneg[low] = A;
  float hs = 0.f;
  hstart[(b*NCH)*8192 + low] = 0.f;
  for (int c = 0; c < NCH-1; c++){
    float S  = sdtb[(b*NCH + c)*512 + d];
    float he = hend[(b*NCH + c)*8192 + low];
    hs = fmaf(__expf(A*S), hs, he);
    hstart[(b*NCH + c + 1)*8192 + low] = hs;
  }
}

// p3': fully parallel correction + D-skip + SiLU gate -> bf16 yg
__global__ __launch_bounds__(256) void k_corr(
    const float* __restrict__ yloc, const float* __restrict__ Scum,
    const float* __restrict__ hstart, const float* __restrict__ Aneg,
    const float* __restrict__ xd, const float* __restrict__ uc,
    const float* __restrict__ uz, const float* __restrict__ Dp,
    unsigned short* __restrict__ yg)
{
  __shared__ float sC[16];
  int row = blockIdx.x, tid = threadIdx.x;
  int b = row >> 10, t = row & 1023, ch = t >> 6;
  if (tid < 16) sC[tid] = xd[row*48 + 32 + tid];
  __syncthreads();
  #pragma unroll
  for (int rep = 0; rep < 2; rep++){
    int d = tid + rep*256;
    float Ss = Scum[row*512 + d];
    float y  = yloc[row*512 + d];
    const float* hs = hstart + ((b*16 + ch)*512 + d)*16;
    const float* An = Aneg + d*16;
    #pragma unroll
    for (int n = 0; n < 16; n++)
      y = fmaf(__expf(An[n]*Ss)*hs[n], sC[n], y);
    float uv = uc[row*512 + d];
    y = fmaf(uv, Dp[d], y);
    float zv = uz[row*1024 + 512 + d];
    yg[row*512 + d] = f2bf(y*(zv/(1.f + __expf(-zv))));
  }
}

// ---------------- scale scan: single-chunk full serial (DS=8), z-batched ---
__global__ __launch_bounds__(64) void k_scan_sc(
    const float* __restrict__ dt, const float* __restrict__ uc,
    const float* __restrict__ uz, const float* __restrict__ xd,
    const float* __restrict__ Alogb, const float* __restrict__ Dpb,
    unsigned short* __restrict__ yg)
{
  __shared__ float sdt[52][64], suc[52][64], sz[52][64];
  __shared__ float sBC[52][16];
  int tid = threadIdx.x;
  int dblk = blockIdx.x;
  int d = dblk*64 + tid;
  int b = blockIdx.y, z = blockIdx.z;
  int s = (z==0) ? 5 : (z==1) ? 20 : 50;
  int roff = (z==0) ? 0 : (z==1) ? 64 : 192;
  const float* Alog = Alogb + z*4096;
  const float* Dp   = Dpb + z*512;
  float A[8];
  #pragma unroll
  for (int n = 0; n < 8; n++) A[n] = -__expf(Alog[d*8 + n]);
  float Dv = Dp[d];
  for (int e = tid; e < s*16; e += 64){
    int t = e >> 4, q = (e & 15)*4;
    long row = (long)(roff + b*s + t);
    *(float4*)&sdt[t][q] = *(const float4*)(dt + row*512 + dblk*64 + q);
    *(float4*)&suc[t][q] = *(const float4*)(uc + row*512 + dblk*64 + q);
    *(float4*)&sz[t][q]  = *(const float4*)(uz + row*1024 + 512 + dblk*64 + q);
  }
  for (int e = tid; e < s*4; e += 64){
    int t = e >> 2, q = (e & 3)*4;
    long row = (long)(roff + b*s + t);
    *(float4*)&sBC[t][q] = *(const float4*)(xd + row*32 + 16 + q);
  }
  __syncthreads();
  float h[8];
  #pragma unroll
  for (int n = 0; n < 8; n++) h[n] = 0.f;
  for (int t = 0; t < s; t++){
    float dtv = sdt[t][tid];
    float uv  = suc[t][tid];
    float zv  = sz[t][tid];
    float du = dtv*uv;
    float y = 0.f;
    #pragma unroll
    for (int n = 0; n < 8; n++){
      h[n] = fmaf(__expf(dtv*A[n]), h[n], du*sBC[t][n]);
      y = fmaf(h[n], sBC[t][8+n], y);
    }
    y = fmaf(uv, Dv, y);
    float gate = zv/(1.f + __expf(-zv));
    yg[(long)(roff + b*s + t)*512 + d] = f2bf(y*gate);
  }
}

__global__ void k_zero(float* p, int n){
  int i = blockIdx.x*256 + threadIdx.x;
  if (i < n) p[i] = 0.f;
}

// ================== single-kernel tail ====================================
// grid = B blocks x 1024 threads. Wave-per-column GEMM phases from LDS.
template<int M>
__device__ __forceinline__ void wgemm(
    const float* in, int K,
    const float* __restrict__ W, const float* __restrict__ bias,
    float* outp, int N, int ostr, int act,
    const float* resid, int rstr)
{
  int tid = threadIdx.x;
  int wave = tid >> 6, lane = tid & 63;
  for (int c = wave; c < N; c += 16){
    float acc[M];
    #pragma unroll
    for (int r = 0; r < M; r++) acc[r] = 0.f;
    for (int k = lane*4; k < K; k += 256){
      float4 w4 = *(const float4*)(W + c*K + k);
      #pragma unroll
      for (int r = 0; r < M; r++){
        float4 x4 = *(const float4*)(in + r*K + k);
        acc[r] = fmaf(x4.x,w4.x,fmaf(x4.y,w4.y,fmaf(x4.z,w4.z,fmaf(x4.w,w4.w,acc[r]))));
      }
    }
    #pragma unroll
    for (int r = 0; r < M; r++){
      #pragma unroll
      for (int o = 32; o > 0; o >>= 1) acc[r] += __shfl_down(acc[r], o, 64);
    }
    if (lane == 0){
      float bv = bias[c];
      #pragma unroll
      for (int r = 0; r < M; r++){
        float v = acc[r] + bv;
        if (act == 1) v = geluf(v);
        if (resid) v += resid[r*rstr + c];
        outp[r*ostr + c] = v;
      }
    }
  }
}

__device__ __forceinline__ void tail_att(const float* qkv, float* att, float* ov){
  int tid = threadIdx.x;
  if (tid < 36){
    int hh = tid/9, r = (tid%9)/3, c = tid%3;
    float s = 0.f;
    const float* qp = qkv + r*768 + hh*64;
    const float* kp = qkv + c*768 + 256 + hh*64;
    for (int k = 0; k < 64; k++) s += qp[k]*kp[k];
    att[hh*9 + r*3 + c] = s*0.125f;
  }
  __syncthreads();
  if (tid < 12){
    int hh = tid/3, r = tid%3;
    float a0 = att[hh*9+r*3+0], a1 = att[hh*9+r*3+1], a2 = att[hh*9+r*3+2];
    float m = fmaxf(a0, fmaxf(a1, a2));
    float e0 = expf(a0-m), e1 = expf(a1-m), e2 = expf(a2-m);
    float s = e0+e1+e2;
    att[hh*9+r*3+0] = e0/s; att[hh*9+r*3+1] = e1/s; att[hh*9+r*3+2] = e2/s;
  }
  __syncthreads();
  if (tid < 768){
    int p = tid >> 8, i = tid & 255, hh = i >> 6;
    ov[p*256 + i] = att[hh*9+p*3+0]*qkv[0*768+512+i]
                  + att[hh*9+p*3+1]*qkv[1*768+512+i]
                  + att[hh*9+p*3+2]*qkv[2*768+512+i];
  }
  __syncthreads();
}

__device__ __forceinline__ void tail_ln3(const float* in, float* outp,
    const float* g, const float* bb, float* red1, float* red2){
  int tid = threadIdx.x;
  float v = 0.f;
  int p = tid >> 8, c = tid & 255;
  if (tid < 768){
    v = in[p*256 + c];
    float s1 = v, s2 = v*v;
    #pragma unroll
    for (int o = 32; o > 0; o >>= 1){ s1 += __shfl_down(s1,o,64); s2 += __shfl_down(s2,o,64); }
    if ((tid & 63) == 0){ red1[tid>>6] = s1; red2[tid>>6] = s2; }
  }
  __syncthreads();
  if (tid < 768){
    float S1 = red1[p*4+0]+red1[p*4+1]+red1[p*4+2]+red1[p*4+3];
    float S2 = red2[p*4+0]+red2[p*4+1]+red2[p*4+2]+red2[p*4+3];
    float m = S1*(1.f/256.f);
    float var = S2*(1.f/256.f) - m*m;
    outp[p*256 + c] = (v - m)*rsqrtf(var + 1e-5f)*g[c] + bb[c];
  }
  __syncthreads();
}

__global__ __launch_bounds__(1024) void k_tail(
    const float* __restrict__ stack,
    const float* fqw, const float* fqb, const float* fow, const float* fob,
    const float* msw, const float* msb,
    const float* l1g, const float* l1b, const float* l2g, const float* l2b,
    const float* sqw, const float* sqb, const float* sow, const float* sob,
    const float* f1w, const float* f1b, const float* f2w, const float* f2b,
    const float* e1w, const float* e1b, const float* e2w, const float* e2b,
    const float* t1w, const float* t1b, const float* t2w, const float* t2b,
    const float* ew, const float* eb,
    float* __restrict__ out)
{
  __shared__ float st[768], lnr[768], qkv[2304], att[36], ov[768], mo[768];
  __shared__ float s2[768], hid[3072], s2f[768], fusedv[256], finalv[256];
  __shared__ float evh[256], tth[128], sv[48];
  __shared__ float red1[12], red2[12];
  int b = blockIdx.x, tid = threadIdx.x;

  if (tid < 768) st[tid] = stack[b*768 + tid];
  __syncthreads();

  // fused path
  wgemm<3>(st, 256, fqw, fqb, qkv, 768, 768, 0, nullptr, 0);
  __syncthreads();
  tail_att(qkv, att, ov);
  wgemm<3>(ov, 256, fow, fob, mo, 256, 256, 0, nullptr, 0);
  __syncthreads();
  wgemm<1>(mo, 768, msw, msb, fusedv, 256, 256, 0, nullptr, 0);
  __syncthreads();

  // sa path
  tail_ln3(st, lnr, l1g, l1b, red1, red2);
  wgemm<3>(lnr, 256, sqw, sqb, qkv, 768, 768, 0, nullptr, 0);
  __syncthreads();
  tail_att(qkv, att, ov);
  wgemm<3>(ov, 256, sow, sob, s2, 256, 256, 0, st, 256);
  __syncthreads();
  tail_ln3(s2, lnr, l2g, l2b, red1, red2);
  wgemm<3>(lnr, 256, f1w, f1b, hid, 1024, 1024, 1, nullptr, 0);
  __syncthreads();
  wgemm<3>(hid, 1024, f2w, f2b, s2f, 256, 256, 0, s2, 256);
  __syncthreads();

  if (tid < 256)
    finalv[tid] = fusedv[tid] + (s2f[tid] + s2f[256+tid] + s2f[512+tid])*(1.f/3.f);
  __syncthreads();

  // heads
  wgemm<1>(finalv, 256, e1w, e1b, evh, 256, 256, 1, nullptr, 0);
  __syncthreads();
  wgemm<1>(evh, 256, e2w, e2b, sv, 7, 7, 0, nullptr, 0);
  __syncthreads();
  wgemm<1>(finalv, 256, t1w, t1b, tth, 128, 128, 1, nullptr, 0);
  __syncthreads();
  wgemm<1>(tth, 128, t2w, t2b, sv + 16, 12, 12, 0, nullptr, 0);
  float* ob = out + b*162;
  wgemm<1>(finalv, 256, ew, eb, ob + 34, 128, 128, 0, nullptr, 0);
  __syncthreads();

  if (tid < 7) sv[32 + tid] = softplusf_(sv[tid]);
  __syncthreads();
  if (tid == 0){
    float s = 0.f;
    for (int j = 0; j < 7; j++) s += sv[32+j] + 1.f;
    sv[40] = s;
  }
  __syncthreads();
  float S = sv[40];
  if (tid < 7){
    float ev = sv[32 + tid], al = ev + 1.f;
    ob[tid] = al / S;
    ob[7 + tid] = ev;
    ob[14 + tid] = al;
  }
  if (tid == 0) ob[21] = 7.f / S;
  if (tid < 6){
    ob[22 + tid] = softplusf_(sv[16 + tid]);
    ob[28 + tid] = expf(0.5f*sv[16 + 6 + tid]);
  }
}

// ---------------------------------------------------------------------------
extern "C" void kernel_launch(void* const* d_in, const int* in_sizes, int n_in,
                              void* d_out, int out_size, void* d_ws, size_t ws_size,
                              hipStream_t stream)
{
  const float* x         = (const float*)d_in[0];
  const float* in_w      = (const float*)d_in[1];
  const float* in_b      = (const float*)d_in[2];
  const float* in_ln_g   = (const float*)d_in[3];
  const float* in_ln_b   = (const float*)d_in[4];
  const float* mb_ln_g   = (const float*)d_in[5];
  const float* mb_ln_b   = (const float*)d_in[6];
  const float* mb_in_w   = (const float*)d_in[7];
  const float* mb_conv_w = (const float*)d_in[8];
  const float* mb_conv_b = (const float*)d_in[9];
  const float* mb_xp_w   = (const float*)d_in[10];
  const float* mb_dt_w   = (const float*)d_in[11];
  const float* mb_dt_b   = (const float*)d_in[12];
  const float* mb_Alog   = (const float*)d_in[13];
  const float* mb_D      = (const float*)d_in[14];
  const float* mb_out_w  = (const float*)d_in[15];
  const float* sc_ln_g   = (const float*)d_in[16];
  const float* sc_ln_b   = (const float*)d_in[17];
  const float* sc_in_w   = (const float*)d_in[18];
  const float* sc_conv_w = (const float*)d_in[19];
  const float* sc_conv_b = (const float*)d_in[20];
  const float* sc_xp_w   = (const float*)d_in[21];
  const float* sc_dt_w   = (const float*)d_in[22];
  const float* sc_dt_b   = (const float*)d_in[23];
  const float* sc_Alog   = (const float*)d_in[24];
  const float* sc_D      = (const float*)d_in[25];
  const float* sc_out_w  = (const float*)d_in[26];
  const float* fus_qkv_w = (const float*)d_in[27];
  const float* fus_qkv_b = (const float*)d_in[28];
  const float* fus_out_w = (const float*)d_in[29];
  const float* fus_out_b = (const float*)d_in[30];
  const float* ms_out_w  = (const float*)d_in[31];
  const float* ms_out_b  = (const float*)d_in[32];
  const float* sa_ln1_g  = (const float*)d_in[33];
  const float* sa_ln1_b  = (const float*)d_in[34];
  const float* sa_ln2_g  = (const float*)d_in[35];
  const float* sa_ln2_b  = (const float*)d_in[36];
  const float* sa_qkv_w  = (const float*)d_in[37];
  const float* sa_qkv_b  = (const float*)d_in[38];
  const float* sa_out_w  = (const float*)d_in[39];
  const float* sa_out_b  = (const float*)d_in[40];
  const float* sa_ff1_w  = (const float*)d_in[41];
  const float* sa_ff1_b  = (const float*)d_in[42];
  const float* sa_ff2_w  = (const float*)d_in[43];
  const float* sa_ff2_b  = (const float*)d_in[44];
  const float* ev1_w     = (const float*)d_in[45];
  const float* ev1_b     = (const float*)d_in[46];
  const float* ev2_w     = (const float*)d_in[47];
  const float* ev2_b     = (const float*)d_in[48];
  const float* ttf1_w    = (const float*)d_in[49];
  const float* ttf1_b    = (const float*)d_in[50];
  const float* ttf2_w    = (const float*)d_in[51];
  const float* ttf2_b    = (const float*)d_in[52];
  const float* emb_w     = (const float*)d_in[53];
  const float* emb_b     = (const float*)d_in[54];

  float* ws = (float*)d_ws;
  float* h     = ws;                        // 1,048,576
  float* uz    = h    + 1048576;            // 4,194,304
  float* uc    = uz   + 4194304;            // 2,097,152
  float* dtb_  = uc   + 2097152;            // 2,097,152
  float* xd    = dtb_ + 2097152;            // 196,608
  float* stack = xd   + 196608;             // 4,096
  float* hend   = stack + 4096;          // 524,288
  float* hstart = hend + 524288;         // 524,288
  float* sdtb   = hstart + 524288;       // 32,768
  float* yloc   = sdtb + 32768;          // 2,097,152
  float* Scum   = yloc + 2097152;        // 2,097,152
  float* Aneg   = Scum + 2097152;        // 8,192
  float* fp32_end = Aneg + 8192;
  unsigned short* bfb = (unsigned short*)fp32_end;
  unsigned short* xnb    = bfb;                  // 1,048,576
  unsigned short* ucb    = xnb + 1048576;        // 2,097,152
  unsigned short* ygb    = ucb + 2097152;        // 2,097,152
  unsigned short* wmbin  = ygb + 2097152;        // 1,048,576
  unsigned short* wmbout = wmbin + 1048576;      // 524,288
  unsigned short* wmbxp  = wmbout + 524288;      // 98,304
  unsigned short* wscin  = wmbxp + 98304;        // 786,432
  unsigned short* wscout = wscin + 786432;       // 393,216
  unsigned short* wscxp  = wscout + 393216;      // 49,152

  k_f2b_all<<<2832, 256, 0, stream>>>(mb_in_w, wmbin, mb_out_w, wmbout, mb_xp_w, wmbxp,
                                      sc_in_w, wscin, sc_out_w, wscout, sc_xp_w, wscxp);

  k_inproj<<<4096, 256, 0, stream>>>(x, in_w, in_b, in_ln_g, in_ln_b, h);

  for (int l = 0; l < 4; l++){
    const float* Al = mb_Alog + l*8192;
    k_ln<<<4096, 256, 0, stream>>>(h, mb_ln_g + l*256, mb_ln_b + l*256, xnb);
    {
      dim3 g(16, 64);
      k_mm64<0,0><<<g, 256, 0, stream>>>(xnb, wmbin + l*262144, uz,
                                         nullptr, nullptr, 4096, 1024, 256, 0);
    }
    k_conv<<<4096, 256, 0, stream>>>(uz, mb_conv_w + l*2048, mb_conv_b + l*512, uc, ucb);
    {
      dim3 g(1, 64);
      k_mmNdt<3><<<g, 256, 0, stream>>>(ucb, wmbxp + l*24576, xd,
                                        mb_dt_w + l*8192, mb_dt_b + l*512, dtb_, 4096, 512);
    }
    {
      dim3 g(8, 4, 16);
      k_scan_p1y<<<g, 64, 0, stream>>>(dtb_, uc, xd, Al, hend, sdtb, yloc, Scum);
      k_scomb<<<128, 256, 0, stream>>>(hend, sdtb, Al, hstart, Aneg);
      k_corr<<<4096, 256, 0, stream>>>(yloc, Scum, hstart, Aneg, xd, uc, uz,
                                       mb_D + l*512, ygb);
    }
    {
      dim3 g(4, 64);
      k_mm64<1,0><<<g, 256, 0, stream>>>(ygb, wmbout + l*131072, h,
                                         h, nullptr, 4096, 256, 512, 0);
    }
  }

  // ---- scale mambas (batched across the 3 scales), pooled -> stack ----
  k_zero<<<12, 256, 0, stream>>>(stack, 3072);
  k_ln_sc<<<448, 256, 0, stream>>>(h, sc_ln_g, sc_ln_b, xnb);
  {
    dim3 g(16, 7);
    k_mm64<0,1><<<g, 256, 0, stream>>>(xnb, wscin, uz, nullptr, nullptr,
                                       448, 1024, 256, 262144);
  }
  k_conv_sc<<<448, 256, 0, stream>>>(uz, sc_conv_w, sc_conv_b, uc, ucb);
  {
    dim3 g(1, 7);
    k_mmNdt_sc<<<g, 256, 0, stream>>>(ucb, wscxp, xd, sc_dt_w, sc_dt_b, dtb_, 448, 512);
  }
  {
    dim3 g(8, 4, 3);
    k_scan_sc<<<g, 64, 0, stream>>>(dtb_, uc, uz, xd, sc_Alog, sc_D, ygb);
  }
  {
    dim3 g(4, 7);
    k_mm64<2,1><<<g, 256, 0, stream>>>(ygb, wscout, nullptr, h, stack,
                                       448, 256, 512, 131072);
  }

  // ---- tail: one kernel ----
  k_tail<<<4, 1024, 0, stream>>>(stack,
      fus_qkv_w, fus_qkv_b, fus_out_w, fus_out_b,
      ms_out_w, ms_out_b,
      sa_ln1_g, sa_ln1_b, sa_ln2_g, sa_ln2_b,
      sa_qkv_w, sa_qkv_b, sa_out_w, sa_out_b,
      sa_ff1_w, sa_ff1_b, sa_ff2_w, sa_ff2_b,
      ev1_w, ev1_b, ev2_w, ev2_b,
      ttf1_w, ttf1_b, ttf2_w, ttf2_b,
      emb_w, emb_b,
      (float*)d_out);
}

// Round 8
// 825.067 us; speedup vs baseline: 1.2702x; 1.2702x over previous
//
#include <hip/hip_runtime.h>
#include <math.h>

// ---------------------------------------------------------------------------
// MambaPredictor forward. R7: R6 scan/dt/scale improvements + R4-style
// wide multi-kernel tail (single-kernel tail regressed: 4 blocks can't
// hide weight-stream latency; grid width beats launch fusion there).
// B=4 L=1024 NF=64 DM=256 DS=16 SCS=8 NL=4 DI=512 DTR=16 DC=4 NFM=6 NH=4
// ---------------------------------------------------------------------------

typedef short short8v __attribute__((ext_vector_type(8)));
typedef float f32x4   __attribute__((ext_vector_type(4)));

__device__ __forceinline__ float geluf(float x){ return 0.5f*x*(1.0f + erff(x*0.70710678118654752f)); }
__device__ __forceinline__ float softplusf_(float x){ return (x > 20.f) ? x : log1pf(expf(x)); }
__device__ __forceinline__ unsigned short f2bf(float f){
  unsigned int u = __float_as_uint(f);
  unsigned int r = (u + 0x7FFFu + ((u >> 16) & 1u)) >> 16;
  return (unsigned short)r;
}

// ---------------- merged fp32 -> bf16 weight convert (6 segments) ----------
__global__ __launch_bounds__(256) void k_f2b_all(
    const float* s0, unsigned short* d0,   // 1024 blocks
    const float* s1, unsigned short* d1,   // 512
    const float* s2, unsigned short* d2,   // 96
    const float* s3, unsigned short* d3,   // 768
    const float* s4, unsigned short* d4,   // 384
    const float* s5, unsigned short* d5)   // 48
{
  int blk = blockIdx.x;
  const float* s; unsigned short* d; int base;
  if      (blk < 1024){ s=s0; d=d0; base=0; }
  else if (blk < 1536){ s=s1; d=d1; base=1024; }
  else if (blk < 1632){ s=s2; d=d2; base=1536; }
  else if (blk < 2400){ s=s3; d=d3; base=1632; }
  else if (blk < 2784){ s=s4; d=d4; base=2400; }
  else                { s=s5; d=d5; base=2784; }
  int i = ((blk - base)*256 + threadIdx.x)*4;
  float4 v = *(const float4*)(s + i);
  *(ushort4*)(d + i) = make_ushort4(f2bf(v.x), f2bf(v.y), f2bf(v.z), f2bf(v.w));
}

// ---------------- initial: h = gelu(LN(x @ in_w^T + in_b)) -----------------
__global__ __launch_bounds__(256) void k_inproj(
    const float* __restrict__ x, const float* __restrict__ w,
    const float* __restrict__ b, const float* __restrict__ g,
    const float* __restrict__ beta, float* __restrict__ h)
{
  __shared__ float xr[64];
  __shared__ float r1[4], r2[4];
  int row = blockIdx.x;
  int tid = threadIdx.x;
  if (tid < 64) xr[tid] = x[row*64 + tid];
  __syncthreads();
  float acc = b[tid];
  const float* wr = w + tid*64;
  #pragma unroll
  for (int k = 0; k < 64; k++) acc += xr[k]*wr[k];
  float s1 = acc, s2 = acc*acc;
  #pragma unroll
  for (int o = 32; o > 0; o >>= 1){ s1 += __shfl_down(s1,o,64); s2 += __shfl_down(s2,o,64); }
  if ((tid & 63) == 0){ r1[tid>>6] = s1; r2[tid>>6] = s2; }
  __syncthreads();
  float S1 = r1[0]+r1[1]+r1[2]+r1[3];
  float S2 = r2[0]+r2[1]+r2[2]+r2[3];
  float m = S1*(1.f/256.f);
  float var = S2*(1.f/256.f) - m*m;
  float xn = (acc - m)*rsqrtf(var + 1e-5f)*g[tid] + beta[tid];
  h[row*256 + tid] = geluf(xn);
}

// ---------------- LayerNorm over 256 -> bf16 (main layers) -----------------
__global__ __launch_bounds__(256) void k_ln(
    const float* __restrict__ src, const float* __restrict__ g, const float* __restrict__ beta,
    unsigned short* __restrict__ dst)
{
  __shared__ float r1[4], r2[4];
  int r = blockIdx.x, tid = threadIdx.x;
  float v = src[r*256 + tid];
  float s1 = v, s2 = v*v;
  #pragma unroll
  for (int o = 32; o > 0; o >>= 1){ s1 += __shfl_down(s1,o,64); s2 += __shfl_down(s2,o,64); }
  if ((tid & 63) == 0){ r1[tid>>6] = s1; r2[tid>>6] = s2; }
  __syncthreads();
  float S1 = r1[0]+r1[1]+r1[2]+r1[3];
  float S2 = r2[0]+r2[1]+r2[2]+r2[3];
  float m = S1*(1.f/256.f);
  float var = S2*(1.f/256.f) - m*m;
  dst[r*256 + tid] = f2bf((v - m)*rsqrtf(var + 1e-5f)*g[tid] + beta[tid]);
}

// ---------------- batched scale regions ------------------------------------
__device__ __forceinline__ void sc_region(int r, int& z, int& roff, int& s){
  if (r < 64){ z=0; roff=0; s=5; }
  else if (r < 192){ z=1; roff=64; s=20; }
  else { z=2; roff=192; s=50; }
}

__global__ __launch_bounds__(256) void k_ln_sc(
    const float* __restrict__ h, const float* __restrict__ gb, const float* __restrict__ bb,
    unsigned short* __restrict__ dst)
{
  __shared__ float r1[4], r2[4];
  int r = blockIdx.x, tid = threadIdx.x;
  int z, roff, s; sc_region(r, z, roff, s);
  int local = r - roff;
  if (local >= 4*s) return;
  int b = local / s, t = local % s;
  float v = h[(b*1024 + (1024 - s) + t)*256 + tid];
  const float* g = gb + z*256; const float* be = bb + z*256;
  float s1 = v, s2 = v*v;
  #pragma unroll
  for (int o = 32; o > 0; o >>= 1){ s1 += __shfl_down(s1,o,64); s2 += __shfl_down(s2,o,64); }
  if ((tid & 63) == 0){ r1[tid>>6] = s1; r2[tid>>6] = s2; }
  __syncthreads();
  float S1 = r1[0]+r1[1]+r1[2]+r1[3];
  float S2 = r2[0]+r2[1]+r2[2]+r2[3];
  float m = S1*(1.f/256.f);
  float var = S2*(1.f/256.f) - m*m;
  dst[r*256 + tid] = f2bf((v - m)*rsqrtf(var + 1e-5f)*g[tid] + be[tid]);
}

// ---------------- MFMA GEMM: C = A(M,K)bf16 @ W(N,K)bf16^T, fp32 acc -------
template<int MODE, int SCB>
__global__ __launch_bounds__(256) void k_mm64(
    const unsigned short* __restrict__ A, const unsigned short* __restrict__ Wb,
    float* __restrict__ C,
    const float* __restrict__ resid,
    float* __restrict__ pool_out,
    int M, int N, int K, int wstr)
{
  int tid = threadIdx.x;
  int wave = tid >> 6, lane = tid & 63;
  int mh = wave & 1, nh = wave >> 1;
  int m0 = blockIdx.y*64 + mh*32;
  int n0 = blockIdx.x*64 + nh*32;
  int z = 0, roff = 0, sc = 0;
  const unsigned short* W = Wb;
  if (SCB){ sc_region(blockIdx.y*64, z, roff, sc); W += z*wstr; }
  int lrow = lane & 15, kc = lane >> 4;
  f32x4 acc[2][2] = {{{0.f,0.f,0.f,0.f},{0.f,0.f,0.f,0.f}},{{0.f,0.f,0.f,0.f},{0.f,0.f,0.f,0.f}}};
  for (int k0 = 0; k0 < K; k0 += 32){
    short8v a[2], b[2];
    #pragma unroll
    for (int mi = 0; mi < 2; mi++){
      int r = m0 + mi*16 + lrow; r = min(r, M-1);
      a[mi] = *(const short8v*)(A + r*K + k0 + kc*8);
    }
    #pragma unroll
    for (int ni = 0; ni < 2; ni++){
      int c = n0 + ni*16 + lrow;
      b[ni] = *(const short8v*)(W + c*K + k0 + kc*8);
    }
    #pragma unroll
    for (int mi = 0; mi < 2; mi++)
      #pragma unroll
      for (int ni = 0; ni < 2; ni++)
        acc[mi][ni] = __builtin_amdgcn_mfma_f32_16x16x32_bf16(a[mi], b[ni], acc[mi][ni], 0, 0, 0);
  }
  int rb = kc*4;
  #pragma unroll
  for (int mi = 0; mi < 2; mi++){
    #pragma unroll
    for (int rr = 0; rr < 4; rr++){
      int grow = m0 + mi*16 + rb + rr;
      if (grow >= M) continue;
      #pragma unroll
      for (int ni = 0; ni < 2; ni++){
        int gcol = n0 + ni*16 + lrow;
        float v = acc[mi][ni][rr];
        if (MODE == 0){
          C[grow*N + gcol] = v;
        } else if (MODE == 1){
          C[grow*N + gcol] = resid[grow*256 + gcol] + v;
        } else {
          int local = grow - roff;
          if (local < 4*sc){
            int bb2 = local / sc, t = local % sc;
            float rv = resid[(bb2*1024 + (1024 - sc) + t)*256 + gcol] + v;
            atomicAdd(&pool_out[bb2*768 + z*256 + gcol], rv*(1.f/(float)sc));
          }
        }
      }
    }
  }
}

// ---- xp GEMM (narrow) + fused dt ------------------------------------------
template<int NT>
__global__ __launch_bounds__(256) void k_mmNdt(
    const unsigned short* __restrict__ A, const unsigned short* __restrict__ W,
    float* __restrict__ Cout,
    const float* __restrict__ dtw, const float* __restrict__ dtb,
    float* __restrict__ dtout, int M, int K)
{
  __shared__ float sxd[64][16];
  int tid = threadIdx.x;
  int wave = tid >> 6, lane = tid & 63;
  int bm0 = blockIdx.y*64;
  int m0 = bm0 + wave*16;
  int lrow = lane & 15, kc = lane >> 4;
  f32x4 acc[NT];
  #pragma unroll
  for (int ni = 0; ni < NT; ni++) acc[ni] = (f32x4){0.f,0.f,0.f,0.f};
  for (int k0 = 0; k0 < K; k0 += 32){
    int r = m0 + lrow; r = min(r, M-1);
    short8v a = *(const short8v*)(A + r*K + k0 + kc*8);
    #pragma unroll
    for (int ni = 0; ni < NT; ni++){
      short8v b = *(const short8v*)(W + (ni*16 + lrow)*K + k0 + kc*8);
      acc[ni] = __builtin_amdgcn_mfma_f32_16x16x32_bf16(a, b, acc[ni], 0, 0, 0);
    }
  }
  int rb = kc*4;
  #pragma unroll
  for (int rr = 0; rr < 4; rr++){
    int grow = m0 + rb + rr;
    #pragma unroll
    for (int ni = 0; ni < NT; ni++)
      Cout[grow*(NT*16) + ni*16 + lrow] = acc[ni][rr];
    sxd[wave*16 + rb + rr][lrow] = acc[0][rr];
  }
  __syncthreads();
  int d0 = tid, d1 = tid + 256;
  float w0[16], w1[16];
  #pragma unroll
  for (int j = 0; j < 16; j++){ w0[j] = dtw[d0*16 + j]; w1[j] = dtw[d1*16 + j]; }
  float b0 = dtb[d0], b1 = dtb[d1];
  for (int r = 0; r < 64; r++){
    float a0 = b0, a1 = b1;
    #pragma unroll
    for (int j = 0; j < 16; j++){
      float xv = sxd[r][j];
      a0 = fmaf(xv, w0[j], a0);
      a1 = fmaf(xv, w1[j], a1);
    }
    dtout[(bm0 + r)*512 + d0] = softplusf_(a0);
    dtout[(bm0 + r)*512 + d1] = softplusf_(a1);
  }
}

__global__ __launch_bounds__(256) void k_mmNdt_sc(
    const unsigned short* __restrict__ A, const unsigned short* __restrict__ Wb,
    float* __restrict__ Cout,
    const float* __restrict__ dtwb, const float* __restrict__ dtbb,
    float* __restrict__ dtout, int M, int K)
{
  __shared__ float sxd[64][16];
  int tid = threadIdx.x;
  int wave = tid >> 6, lane = tid & 63;
  int bm0 = blockIdx.y*64;
  int z, roff, s; sc_region(bm0, z, roff, s);
  const unsigned short* W = Wb + z*16384;
  const float* dtw = dtwb + z*8192;
  const float* dtb = dtbb + z*512;
  int m0 = bm0 + wave*16;
  int lrow = lane & 15, kc = lane >> 4;
  f32x4 acc[2];
  acc[0] = (f32x4){0.f,0.f,0.f,0.f}; acc[1] = (f32x4){0.f,0.f,0.f,0.f};
  for (int k0 = 0; k0 < K; k0 += 32){
    int r = m0 + lrow; r = min(r, M-1);
    short8v a = *(const short8v*)(A + r*K + k0 + kc*8);
    #pragma unroll
    for (int ni = 0; ni < 2; ni++){
      short8v b = *(const short8v*)(W + (ni*16 + lrow)*K + k0 + kc*8);
      acc[ni] = __builtin_amdgcn_mfma_f32_16x16x32_bf16(a, b, acc[ni], 0, 0, 0);
    }
  }
  int rb = kc*4;
  #pragma unroll
  for (int rr = 0; rr < 4; rr++){
    int grow = m0 + rb + rr;
    #pragma unroll
    for (int ni = 0; ni < 2; ni++)
      Cout[grow*32 + ni*16 + lrow] = acc[ni][rr];
    sxd[wave*16 + rb + rr][lrow] = acc[0][rr];
  }
  __syncthreads();
  int d0 = tid, d1 = tid + 256;
  float w0[16], w1[16];
  #pragma unroll
  for (int j = 0; j < 16; j++){ w0[j] = dtw[d0*16 + j]; w1[j] = dtw[d1*16 + j]; }
  float b0 = dtb[d0], b1 = dtb[d1];
  for (int r = 0; r < 64; r++){
    float a0 = b0, a1 = b1;
    #pragma unroll
    for (int j = 0; j < 16; j++){
      float xv = sxd[r][j];
      a0 = fmaf(xv, w0[j], a0);
      a1 = fmaf(xv, w1[j], a1);
    }
    dtout[(bm0 + r)*512 + d0] = softplusf_(a0);
    dtout[(bm0 + r)*512 + d1] = softplusf_(a1);
  }
}

// ---------------- depthwise causal conv (DC=4) + SiLU ----------------------
__global__ __launch_bounds__(256) void k_conv(
    const float* __restrict__ uz, const float* __restrict__ cw, const float* __restrict__ cb,
    float* __restrict__ uc, unsigned short* __restrict__ ucb)
{
  int row = blockIdx.x;
  int t = row & 1023;
  int tid = threadIdx.x;
  for (int d = tid; d < 512; d += 256){
    float acc = cb[d];
    const float* w = cw + d*4;
    #pragma unroll
    for (int k = 0; k < 4; k++){
      int ts = t - 3 + k;
      if (ts >= 0) acc += uz[(row - (3-k))*1024 + d]*w[k];
    }
    float s = acc/(1.f + expf(-acc));
    uc[row*512 + d] = s;
    ucb[row*512 + d] = f2bf(s);
  }
}

__global__ __launch_bounds__(256) void k_conv_sc(
    const float* __restrict__ uz, const float* __restrict__ cwb, const float* __restrict__ cbb,
    float* __restrict__ uc, unsigned short* __restrict__ ucb)
{
  int row = blockIdx.x;
  int z, roff, s; sc_region(row, z, roff, s);
  int local = row - roff;
  if (local >= 4*s) return;
  int t = local % s;
  const float* cw = cwb + z*2048;
  const float* cb = cbb + z*512;
  int tid = threadIdx.x;
  for (int d = tid; d < 512; d += 256){
    float acc = cb[d];
    const float* w = cw + d*4;
    #pragma unroll
    for (int k = 0; k < 4; k++){
      int ts = t - 3 + k;
      if (ts >= 0) acc += uz[(row - (3-k))*1024 + d]*w[k];
    }
    float sv = acc/(1.f + expf(-acc));
    uc[row*512 + d] = sv;
    ucb[row*512 + d] = f2bf(sv);
  }
}

// ============ chunked scan: p1 (serial local) + p2 + parallel correction ===
__global__ __launch_bounds__(64) void k_scan_p1y(
    const float* __restrict__ dt, const float* __restrict__ uc,
    const float* __restrict__ xd, const float* __restrict__ Alog,
    float* __restrict__ hend, float* __restrict__ sdtb,
    float* __restrict__ yloc, float* __restrict__ Scum)
{
  const int CL = 64, NCH = 16;
  __shared__ float sdt[64][64], suc[64][64];
  __shared__ float sBC[64][32];
  int tid = threadIdx.x;
  int dblk = blockIdx.x;
  int d = dblk*64 + tid;
  int b = blockIdx.y, ch = blockIdx.z;
  int t0 = ch*CL;
  float A[16];
  #pragma unroll
  for (int n = 0; n < 16; n++) A[n] = -__expf(Alog[d*16 + n]);
  for (int e = tid; e < CL*16; e += 64){
    int t = e >> 4, q = (e & 15)*4;
    long off = (long)(b*1024 + t0 + t)*512 + dblk*64 + q;
    *(float4*)&sdt[t][q] = *(const float4*)(dt + off);
    *(float4*)&suc[t][q] = *(const float4*)(uc + off);
  }
  for (int e = tid; e < CL*8; e += 64){
    int t = e >> 3, q = (e & 7)*4;
    *(float4*)&sBC[t][q] = *(const float4*)(xd + (long)(b*1024 + t0 + t)*48 + 16 + q);
  }
  __syncthreads();
  float h[16];
  #pragma unroll
  for (int n = 0; n < 16; n++) h[n] = 0.f;
  float Ss = 0.f;
  #pragma unroll 2
  for (int t = 0; t < CL; t++){
    float dtv = sdt[t][tid];
    float uv  = suc[t][tid];
    Ss += dtv;
    float du = dtv*uv;
    float y = 0.f;
    #pragma unroll
    for (int n = 0; n < 16; n++){
      h[n] = fmaf(__expf(dtv*A[n]), h[n], du*sBC[t][n]);
      y = fmaf(h[n], sBC[t][16+n], y);
    }
    long row = (long)(b*1024 + t0 + t);
    yloc[row*512 + d] = y;
    Scum[row*512 + d] = Ss;
  }
  int base = ((b*NCH + ch)*512 + d)*16;
  #pragma unroll
  for (int q = 0; q < 4; q++)
    *(float4*)(hend + base + q*4) = make_float4(h[q*4], h[q*4+1], h[q*4+2], h[q*4+3]);
  sdtb[(b*NCH + ch)*512 + d] = Ss;
}

__global__ __launch_bounds__(256) void k_scomb(
    const float* __restrict__ hend, const float* __restrict__ sdtb,
    const float* __restrict__ Alog, float* __restrict__ hstart,
    float* __restrict__ Aneg)
{
  const int NCH = 16;
  int idx = blockIdx.x*256 + threadIdx.x;
  int low = idx & 8191;
  int d = (idx >> 4) & 511, b = idx >> 13;
  float A = -__expf(Alog[low]);
  if (b == 0) Aneg[low] = A;
  float hs = 0.f;
  hstart[(b*NCH)*8192 + low] = 0.f;
  for (int c = 0; c < NCH-1; c++){
    float S  = sdtb[(b*NCH + c)*512 + d];
    float he = hend[(b*NCH + c)*8192 + low];
    hs = fmaf(__expf(A*S), hs, he);
    hstart[(b*NCH + c + 1)*8192 + low] = hs;
  }
}

__global__ __launch_bounds__(256) void k_corr(
    const float* __restrict__ yloc, const float* __restrict__ Scum,
    const float* __restrict__ hstart, const float* __restrict__ Aneg,
    const float* __restrict__ xd, const float* __restrict__ uc,
    const float* __restrict__ uz, const float* __restrict__ Dp,
    unsigned short* __restrict__ yg)
{
  __shared__ float sC[16];
  int row = blockIdx.x, tid = threadIdx.x;
  int b = row >> 10, t = row & 1023, ch = t >> 6;
  if (tid < 16) sC[tid] = xd[row*48 + 32 + tid];
  __syncthreads();
  #pragma unroll
  for (int rep = 0; rep < 2; rep++){
    int d = tid + rep*256;
    float Ss = Scum[row*512 + d];
    float y  = yloc[row*512 + d];
    const float* hs = hstart + ((b*16 + ch)*512 + d)*16;
    const float* An = Aneg + d*16;
    #pragma unroll
    for (int n = 0; n < 16; n++)
      y = fmaf(__expf(An[n]*Ss)*hs[n], sC[n], y);
    float uv = uc[row*512 + d];
    y = fmaf(uv, Dp[d], y);
    float zv = uz[row*1024 + 512 + d];
    yg[row*512 + d] = f2bf(y*(zv/(1.f + __expf(-zv))));
  }
}

// ---------------- scale scan (DS=8, z-batched, single chunk) ---------------
__global__ __launch_bounds__(64) void k_scan_sc(
    const float* __restrict__ dt, const float* __restrict__ uc,
    const float* __restrict__ uz, const float* __restrict__ xd,
    const float* __restrict__ Alogb, const float* __restrict__ Dpb,
    unsigned short* __restrict__ yg)
{
  __shared__ float sdt[52][64], suc[52][64], sz[52][64];
  __shared__ float sBC[52][16];
  int tid = threadIdx.x;
  int dblk = blockIdx.x;
  int d = dblk*64 + tid;
  int b = blockIdx.y, z = blockIdx.z;
  int s = (z==0) ? 5 : (z==1) ? 20 : 50;
  int roff = (z==0) ? 0 : (z==1) ? 64 : 192;
  const float* Alog = Alogb + z*4096;
  const float* Dp   = Dpb + z*512;
  float A[8];
  #pragma unroll
  for (int n = 0; n < 8; n++) A[n] = -__expf(Alog[d*8 + n]);
  float Dv = Dp[d];
  for (int e = tid; e < s*16; e += 64){
    int t = e >> 4, q = (e & 15)*4;
    long row = (long)(roff + b*s + t);
    *(float4*)&sdt[t][q] = *(const float4*)(dt + row*512 + dblk*64 + q);
    *(float4*)&suc[t][q] = *(const float4*)(uc + row*512 + dblk*64 + q);
    *(float4*)&sz[t][q]  = *(const float4*)(uz + row*1024 + 512 + dblk*64 + q);
  }
  for (int e = tid; e < s*4; e += 64){
    int t = e >> 2, q = (e & 3)*4;
    long row = (long)(roff + b*s + t);
    *(float4*)&sBC[t][q] = *(const float4*)(xd + row*32 + 16 + q);
  }
  __syncthreads();
  float h[8];
  #pragma unroll
  for (int n = 0; n < 8; n++) h[n] = 0.f;
  for (int t = 0; t < s; t++){
    float dtv = sdt[t][tid];
    float uv  = suc[t][tid];
    float zv  = sz[t][tid];
    float du = dtv*uv;
    float y = 0.f;
    #pragma unroll
    for (int n = 0; n < 8; n++){
      h[n] = fmaf(__expf(dtv*A[n]), h[n], du*sBC[t][n]);
      y = fmaf(h[n], sBC[t][8+n], y);
    }
    y = fmaf(uv, Dv, y);
    float gate = zv/(1.f + __expf(-zv));
    yg[(long)(roff + b*s + t)*512 + d] = f2bf(y*gate);
  }
}

__global__ void k_zero(float* p, int n){
  int i = blockIdx.x*256 + threadIdx.x;
  if (i < n) p[i] = 0.f;
}

// ================== tail kernels (wide, multi-kernel) ======================
// wave-per-column GEMM: out(M,N) = act(A(M,K) @ W(N,K)^T + bias) [+resid]
template<int M, int ACT, int RES>
__global__ __launch_bounds__(256) void k_tw(
    const float* __restrict__ A, const float* __restrict__ W,
    const float* __restrict__ bias, float* __restrict__ out,
    const float* __restrict__ resid, int N, int K, int ostride, int ocoff)
{
  extern __shared__ float sx[];
  int tid = threadIdx.x;
  for (int e = tid*4; e < M*K; e += 1024)
    *(float4*)&sx[e] = *(const float4*)(A + e);
  __syncthreads();
  int wave = tid >> 6, lane = tid & 63;
  int c = blockIdx.x*4 + wave;
  if (c >= N) return;
  float acc[M];
  #pragma unroll
  for (int r = 0; r < M; r++) acc[r] = 0.f;
  for (int k = lane*4; k < K; k += 256){
    float4 w4 = *(const float4*)(W + c*K + k);
    #pragma unroll
    for (int r = 0; r < M; r++){
      float4 x4 = *(float4*)&sx[r*K + k];
      acc[r] = fmaf(x4.x,w4.x,fmaf(x4.y,w4.y,fmaf(x4.z,w4.z,fmaf(x4.w,w4.w,acc[r]))));
    }
  }
  #pragma unroll
  for (int r = 0; r < M; r++){
    #pragma unroll
    for (int o = 32; o > 0; o >>= 1) acc[r] += __shfl_down(acc[r], o, 64);
  }
  if (lane == 0){
    float bv = bias[c];
    #pragma unroll
    for (int r = 0; r < M; r++){
      float v = acc[r] + bv;
      if (ACT == 1) v = geluf(v);
      if (RES == 1) v += resid[r*256 + c];
      out[r*ostride + ocoff + c] = v;
    }
  }
}

__global__ __launch_bounds__(256) void k_t_ln(
    const float* __restrict__ src, const float* __restrict__ g, const float* __restrict__ b,
    float* __restrict__ dst)
{
  __shared__ float r1[4], r2[4];
  int r = blockIdx.x, tid = threadIdx.x;
  float v = src[r*256 + tid];
  float s1 = v, s2 = v*v;
  #pragma unroll
  for (int o = 32; o > 0; o >>= 1){ s1 += __shfl_down(s1,o,64); s2 += __shfl_down(s2,o,64); }
  if ((tid & 63) == 0){ r1[tid>>6] = s1; r2[tid>>6] = s2; }
  __syncthreads();
  float S1 = r1[0]+r1[1]+r1[2]+r1[3];
  float S2 = r2[0]+r2[1]+r2[2]+r2[3];
  float m = S1*(1.f/256.f);
  float var = S2*(1.f/256.f) - m*m;
  dst[r*256 + tid] = (v - m)*rsqrtf(var + 1e-5f)*g[tid] + b[tid];
}

__global__ __launch_bounds__(256) void k_t_att(
    const float* __restrict__ qkv, float* __restrict__ ov)
{
  __shared__ float att[36];
  int b = blockIdx.x, tid = threadIdx.x;
  if (tid < 36){
    int hh = tid/9, r = (tid%9)/3, c = tid%3;
    float s = 0.f;
    const float* qp = qkv + (b*3 + r)*768 + hh*64;
    const float* kp = qkv + (b*3 + c)*768 + 256 + hh*64;
    for (int k = 0; k < 64; k++) s += qp[k]*kp[k];
    att[hh*9 + r*3 + c] = s*0.125f;
  }
  __syncthreads();
  if (tid < 12){
    int hh = tid/3, r = tid%3;
    float a0 = att[hh*9+r*3+0], a1 = att[hh*9+r*3+1], a2 = att[hh*9+r*3+2];
    float m = fmaxf(a0, fmaxf(a1, a2));
    float e0 = expf(a0-m), e1 = expf(a1-m), e2 = expf(a2-m);
    float s = e0+e1+e2;
    att[hh*9+r*3+0] = e0/s; att[hh*9+r*3+1] = e1/s; att[hh*9+r*3+2] = e2/s;
  }
  __syncthreads();
  for (int e = tid; e < 768; e += 256){
    int p = e >> 8, i = e & 255, hh = i >> 6;
    ov[(b*3 + p)*256 + i] = att[hh*9+p*3+0]*qkv[(b*3+0)*768+512+i]
                          + att[hh*9+p*3+1]*qkv[(b*3+1)*768+512+i]
                          + att[hh*9+p*3+2]*qkv[(b*3+2)*768+512+i];
  }
}

__global__ __launch_bounds__(256) void k_t_final(
    const float* __restrict__ fusedv, const float* __restrict__ s2f, float* __restrict__ finalv)
{
  int b = blockIdx.x, c = threadIdx.x;
  finalv[b*256 + c] = fusedv[b*256 + c] +
    (s2f[(b*3+0)*256 + c] + s2f[(b*3+1)*256 + c] + s2f[(b*3+2)*256 + c])*(1.f/3.f);
}

__global__ __launch_bounds__(64) void k_t_fin(
    const float* __restrict__ evraw, const float* __restrict__ ttraw, float* __restrict__ out)
{
  __shared__ float ev[7];
  __shared__ float S;
  int b = blockIdx.x, tid = threadIdx.x;
  if (tid < 7) ev[tid] = softplusf_(evraw[b*7 + tid]);
  __syncthreads();
  if (tid == 0){
    float s = 0.f;
    for (int j = 0; j < 7; j++) s += ev[j] + 1.f;
    S = s;
  }
  __syncthreads();
  float* ob = out + b*162;
  if (tid < 7){
    float al = ev[tid] + 1.f;
    ob[tid] = al / S;
    ob[7 + tid] = ev[tid];
    ob[14 + tid] = al;
  }
  if (tid == 0) ob[21] = 7.f / S;
  if (tid < 6){
    ob[22 + tid] = softplusf_(ttraw[b*12 + tid]);
    ob[28 + tid] = expf(0.5f*ttraw[b*12 + 6 + tid]);
  }
}

// ---------------------------------------------------------------------------
extern "C" void kernel_launch(void* const* d_in, const int* in_sizes, int n_in,
                              void* d_out, int out_size, void* d_ws, size_t ws_size,
                              hipStream_t stream)
{
  const float* x         = (const float*)d_in[0];
  const float* in_w      = (const float*)d_in[1];
  const float* in_b      = (const float*)d_in[2];
  const float* in_ln_g   = (const float*)d_in[3];
  const float* in_ln_b   = (const float*)d_in[4];
  const float* mb_ln_g   = (const float*)d_in[5];
  const float* mb_ln_b   = (const float*)d_in[6];
  const float* mb_in_w   = (const float*)d_in[7];
  const float* mb_conv_w = (const float*)d_in[8];
  const float* mb_conv_b = (const float*)d_in[9];
  const float* mb_xp_w   = (const float*)d_in[10];
  const float* mb_dt_w   = (const float*)d_in[11];
  const float* mb_dt_b   = (const float*)d_in[12];
  const float* mb_Alog   = (const float*)d_in[13];
  const float* mb_D      = (const float*)d_in[14];
  const float* mb_out_w  = (const float*)d_in[15];
  const float* sc_ln_g   = (const float*)d_in[16];
  const float* sc_ln_b   = (const float*)d_in[17];
  const float* sc_in_w   = (const float*)d_in[18];
  const float* sc_conv_w = (const float*)d_in[19];
  const float* sc_conv_b = (const float*)d_in[20];
  const float* sc_xp_w   = (const float*)d_in[21];
  const float* sc_dt_w   = (const float*)d_in[22];
  const float* sc_dt_b   = (const float*)d_in[23];
  const float* sc_Alog   = (const float*)d_in[24];
  const float* sc_D      = (const float*)d_in[25];
  const float* sc_out_w  = (const float*)d_in[26];
  const float* fus_qkv_w = (const float*)d_in[27];
  const float* fus_qkv_b = (const float*)d_in[28];
  const float* fus_out_w = (const float*)d_in[29];
  const float* fus_out_b = (const float*)d_in[30];
  const float* ms_out_w  = (const float*)d_in[31];
  const float* ms_out_b  = (const float*)d_in[32];
  const float* sa_ln1_g  = (const float*)d_in[33];
  const float* sa_ln1_b  = (const float*)d_in[34];
  const float* sa_ln2_g  = (const float*)d_in[35];
  const float* sa_ln2_b  = (const float*)d_in[36];
  const float* sa_qkv_w  = (const float*)d_in[37];
  const float* sa_qkv_b  = (const float*)d_in[38];
  const float* sa_out_w  = (const float*)d_in[39];
  const float* sa_out_b  = (const float*)d_in[40];
  const float* sa_ff1_w  = (const float*)d_in[41];
  const float* sa_ff1_b  = (const float*)d_in[42];
  const float* sa_ff2_w  = (const float*)d_in[43];
  const float* sa_ff2_b  = (const float*)d_in[44];
  const float* ev1_w     = (const float*)d_in[45];
  const float* ev1_b     = (const float*)d_in[46];
  const float* ev2_w     = (const float*)d_in[47];
  const float* ev2_b     = (const float*)d_in[48];
  const float* ttf1_w    = (const float*)d_in[49];
  const float* ttf1_b    = (const float*)d_in[50];
  const float* ttf2_w    = (const float*)d_in[51];
  const float* ttf2_b    = (const float*)d_in[52];
  const float* emb_w     = (const float*)d_in[53];
  const float* emb_b     = (const float*)d_in[54];

  float* ws = (float*)d_ws;
  float* h     = ws;                        // 1,048,576
  float* uz    = h    + 1048576;            // 4,194,304
  float* uc    = uz   + 4194304;            // 2,097,152
  float* dtb_  = uc   + 2097152;            // 2,097,152
  float* xd    = dtb_ + 2097152;            // 196,608
  float* stack = xd   + 196608;             // 4,096
  float* hend   = stack + 4096;          // 524,288
  float* hstart = hend + 524288;         // 524,288
  float* sdtb   = hstart + 524288;       // 32,768
  float* yloc   = sdtb + 32768;          // 2,097,152
  float* Scum   = yloc + 2097152;        // 2,097,152
  float* Aneg   = Scum + 2097152;        // 8,192
  // tail buffers
  float* qkvF   = Aneg + 8192;   // 9216
  float* ovF    = qkvF + 9216;   // 3072
  float* moF    = ovF  + 3072;   // 3072
  float* fusedv = moF  + 3072;   // 1024
  float* lnbuf  = fusedv + 1024; // 3072
  float* qkvS   = lnbuf + 3072;  // 9216
  float* ovS    = qkvS + 9216;   // 3072
  float* s2     = ovS  + 3072;   // 3072
  float* ln2r   = s2   + 3072;   // 3072
  float* hid    = ln2r + 3072;   // 12288
  float* s2f    = hid  + 12288;  // 3072
  float* finalv = s2f  + 3072;   // 1024
  float* evh    = finalv + 1024; // 1024
  float* tth    = evh  + 1024;   // 512
  float* evraw  = tth  + 512;    // 32
  float* ttraw  = evraw + 32;    // 64
  float* fp32_end = ttraw + 64;
  unsigned short* bfb = (unsigned short*)fp32_end;
  unsigned short* xnb    = bfb;                  // 1,048,576
  unsigned short* ucb    = xnb + 1048576;        // 2,097,152
  unsigned short* ygb    = ucb + 2097152;        // 2,097,152
  unsigned short* wmbin  = ygb + 2097152;        // 1,048,576
  unsigned short* wmbout = wmbin + 1048576;      // 524,288
  unsigned short* wmbxp  = wmbout + 524288;      // 98,304
  unsigned short* wscin  = wmbxp + 98304;        // 786,432
  unsigned short* wscout = wscin + 786432;       // 393,216
  unsigned short* wscxp  = wscout + 393216;      // 49,152

  k_f2b_all<<<2832, 256, 0, stream>>>(mb_in_w, wmbin, mb_out_w, wmbout, mb_xp_w, wmbxp,
                                      sc_in_w, wscin, sc_out_w, wscout, sc_xp_w, wscxp);

  k_inproj<<<4096, 256, 0, stream>>>(x, in_w, in_b, in_ln_g, in_ln_b, h);

  for (int l = 0; l < 4; l++){
    const float* Al = mb_Alog + l*8192;
    k_ln<<<4096, 256, 0, stream>>>(h, mb_ln_g + l*256, mb_ln_b + l*256, xnb);
    {
      dim3 g(16, 64);
      k_mm64<0,0><<<g, 256, 0, stream>>>(xnb, wmbin + l*262144, uz,
                                         nullptr, nullptr, 4096, 1024, 256, 0);
    }
    k_conv<<<4096, 256, 0, stream>>>(uz, mb_conv_w + l*2048, mb_conv_b + l*512, uc, ucb);
    {
      dim3 g(1, 64);
      k_mmNdt<3><<<g, 256, 0, stream>>>(ucb, wmbxp + l*24576, xd,
                                        mb_dt_w + l*8192, mb_dt_b + l*512, dtb_, 4096, 512);
    }
    {
      dim3 g(8, 4, 16);
      k_scan_p1y<<<g, 64, 0, stream>>>(dtb_, uc, xd, Al, hend, sdtb, yloc, Scum);
      k_scomb<<<128, 256, 0, stream>>>(hend, sdtb, Al, hstart, Aneg);
      k_corr<<<4096, 256, 0, stream>>>(yloc, Scum, hstart, Aneg, xd, uc, uz,
                                       mb_D + l*512, ygb);
    }
    {
      dim3 g(4, 64);
      k_mm64<1,0><<<g, 256, 0, stream>>>(ygb, wmbout + l*131072, h,
                                         h, nullptr, 4096, 256, 512, 0);
    }
  }

  // ---- scale mambas (batched), pooled -> stack ----
  k_zero<<<12, 256, 0, stream>>>(stack, 3072);
  k_ln_sc<<<448, 256, 0, stream>>>(h, sc_ln_g, sc_ln_b, xnb);
  {
    dim3 g(16, 7);
    k_mm64<0,1><<<g, 256, 0, stream>>>(xnb, wscin, uz, nullptr, nullptr,
                                       448, 1024, 256, 262144);
  }
  k_conv_sc<<<448, 256, 0, stream>>>(uz, sc_conv_w, sc_conv_b, uc, ucb);
  {
    dim3 g(1, 7);
    k_mmNdt_sc<<<g, 256, 0, stream>>>(ucb, wscxp, xd, sc_dt_w, sc_dt_b, dtb_, 448, 512);
  }
  {
    dim3 g(8, 4, 3);
    k_scan_sc<<<g, 64, 0, stream>>>(dtb_, uc, uz, xd, sc_Alog, sc_D, ygb);
  }
  {
    dim3 g(4, 7);
    k_mm64<2,1><<<g, 256, 0, stream>>>(ygb, wscout, nullptr, h, stack,
                                       448, 256, 512, 131072);
  }

  // ---- tail (wide multi-kernel, proven R4/R5 version) ----
  float* dout = (float*)d_out;
  k_tw<12,0,0><<<192, 256, 12*256*4, stream>>>(stack, fus_qkv_w, fus_qkv_b, qkvF, nullptr, 768, 256, 768, 0);
  k_t_att<<<4, 256, 0, stream>>>(qkvF, ovF);
  k_tw<12,0,0><<<64, 256, 12*256*4, stream>>>(ovF, fus_out_w, fus_out_b, moF, nullptr, 256, 256, 256, 0);
  k_tw<4,0,0><<<64, 256, 4*768*4, stream>>>(moF, ms_out_w, ms_out_b, fusedv, nullptr, 256, 768, 256, 0);
  k_t_ln<<<12, 256, 0, stream>>>(stack, sa_ln1_g, sa_ln1_b, lnbuf);
  k_tw<12,0,0><<<192, 256, 12*256*4, stream>>>(lnbuf, sa_qkv_w, sa_qkv_b, qkvS, nullptr, 768, 256, 768, 0);
  k_t_att<<<4, 256, 0, stream>>>(qkvS, ovS);
  k_tw<12,0,1><<<64, 256, 12*256*4, stream>>>(ovS, sa_out_w, sa_out_b, s2, stack, 256, 256, 256, 0);
  k_t_ln<<<12, 256, 0, stream>>>(s2, sa_ln2_g, sa_ln2_b, ln2r);
  k_tw<12,1,0><<<256, 256, 12*256*4, stream>>>(ln2r, sa_ff1_w, sa_ff1_b, hid, nullptr, 1024, 256, 1024, 0);
  k_tw<12,0,1><<<64, 256, 12*1024*4, stream>>>(hid, sa_ff2_w, sa_ff2_b, s2f, s2, 256, 1024, 256, 0);
  k_t_final<<<4, 256, 0, stream>>>(fusedv, s2f, finalv);
  k_tw<4,1,0><<<64, 256, 4*256*4, stream>>>(finalv, ev1_w, ev1_b, evh, nullptr, 256, 256, 256, 0);
  k_tw<4,0,0><<<2, 256, 4*256*4, stream>>>(evh, ev2_w, ev2_b, evraw, nullptr, 7, 256, 7, 0);
  k_tw<4,1,0><<<32, 256, 4*256*4, stream>>>(finalv, ttf1_w, ttf1_b, tth, nullptr, 128, 256, 128, 0);
  k_tw<4,0,0><<<3, 256, 4*128*4, stream>>>(tth, ttf2_w, ttf2_b, ttraw, nullptr, 12, 128, 12, 0);
  k_tw<4,0,0><<<32, 256, 4*256*4, stream>>>(finalv, emb_w, emb_b, dout, nullptr, 128, 256, 162, 34);
  k_t_fin<<<4, 64, 0, stream>>>(evraw, ttraw, dout);
}

// Round 9
// 735.657 us; speedup vs baseline: 1.4246x; 1.1215x over previous
//
#include <hip/hip_runtime.h>
#include <math.h>

// ---------------------------------------------------------------------------
// MambaPredictor forward. R8: split-K wide xp+dt kernel (k_xpdt), replacing
// the narrow 64-block fused k_mmNdt (grid width beats fusion, again).
// B=4 L=1024 NF=64 DM=256 DS=16 SCS=8 NL=4 DI=512 DTR=16 DC=4 NFM=6 NH=4
// ---------------------------------------------------------------------------

typedef short short8v __attribute__((ext_vector_type(8)));
typedef float f32x4   __attribute__((ext_vector_type(4)));

__device__ __forceinline__ float geluf(float x){ return 0.5f*x*(1.0f + erff(x*0.70710678118654752f)); }
__device__ __forceinline__ float softplusf_(float x){ return (x > 20.f) ? x : log1pf(expf(x)); }
__device__ __forceinline__ unsigned short f2bf(float f){
  unsigned int u = __float_as_uint(f);
  unsigned int r = (u + 0x7FFFu + ((u >> 16) & 1u)) >> 16;
  return (unsigned short)r;
}

// ---------------- merged fp32 -> bf16 weight convert (6 segments) ----------
__global__ __launch_bounds__(256) void k_f2b_all(
    const float* s0, unsigned short* d0,   // 1024 blocks
    const float* s1, unsigned short* d1,   // 512
    const float* s2, unsigned short* d2,   // 96
    const float* s3, unsigned short* d3,   // 768
    const float* s4, unsigned short* d4,   // 384
    const float* s5, unsigned short* d5)   // 48
{
  int blk = blockIdx.x;
  const float* s; unsigned short* d; int base;
  if      (blk < 1024){ s=s0; d=d0; base=0; }
  else if (blk < 1536){ s=s1; d=d1; base=1024; }
  else if (blk < 1632){ s=s2; d=d2; base=1536; }
  else if (blk < 2400){ s=s3; d=d3; base=1632; }
  else if (blk < 2784){ s=s4; d=d4; base=2400; }
  else                { s=s5; d=d5; base=2784; }
  int i = ((blk - base)*256 + threadIdx.x)*4;
  float4 v = *(const float4*)(s + i);
  *(ushort4*)(d + i) = make_ushort4(f2bf(v.x), f2bf(v.y), f2bf(v.z), f2bf(v.w));
}

// ---------------- initial: h = gelu(LN(x @ in_w^T + in_b)) -----------------
__global__ __launch_bounds__(256) void k_inproj(
    const float* __restrict__ x, const float* __restrict__ w,
    const float* __restrict__ b, const float* __restrict__ g,
    const float* __restrict__ beta, float* __restrict__ h)
{
  __shared__ float xr[64];
  __shared__ float r1[4], r2[4];
  int row = blockIdx.x;
  int tid = threadIdx.x;
  if (tid < 64) xr[tid] = x[row*64 + tid];
  __syncthreads();
  float acc = b[tid];
  const float* wr = w + tid*64;
  #pragma unroll
  for (int k = 0; k < 64; k++) acc += xr[k]*wr[k];
  float s1 = acc, s2 = acc*acc;
  #pragma unroll
  for (int o = 32; o > 0; o >>= 1){ s1 += __shfl_down(s1,o,64); s2 += __shfl_down(s2,o,64); }
  if ((tid & 63) == 0){ r1[tid>>6] = s1; r2[tid>>6] = s2; }
  __syncthreads();
  float S1 = r1[0]+r1[1]+r1[2]+r1[3];
  float S2 = r2[0]+r2[1]+r2[2]+r2[3];
  float m = S1*(1.f/256.f);
  float var = S2*(1.f/256.f) - m*m;
  float xn = (acc - m)*rsqrtf(var + 1e-5f)*g[tid] + beta[tid];
  h[row*256 + tid] = geluf(xn);
}

// ---------------- LayerNorm over 256 -> bf16 (main layers) -----------------
__global__ __launch_bounds__(256) void k_ln(
    const float* __restrict__ src, const float* __restrict__ g, const float* __restrict__ beta,
    unsigned short* __restrict__ dst)
{
  __shared__ float r1[4], r2[4];
  int r = blockIdx.x, tid = threadIdx.x;
  float v = src[r*256 + tid];
  float s1 = v, s2 = v*v;
  #pragma unroll
  for (int o = 32; o > 0; o >>= 1){ s1 += __shfl_down(s1,o,64); s2 += __shfl_down(s2,o,64); }
  if ((tid & 63) == 0){ r1[tid>>6] = s1; r2[tid>>6] = s2; }
  __syncthreads();
  float S1 = r1[0]+r1[1]+r1[2]+r1[3];
  float S2 = r2[0]+r2[1]+r2[2]+r2[3];
  float m = S1*(1.f/256.f);
  float var = S2*(1.f/256.f) - m*m;
  dst[r*256 + tid] = f2bf((v - m)*rsqrtf(var + 1e-5f)*g[tid] + beta[tid]);
}

// ---------------- batched scale regions ------------------------------------
__device__ __forceinline__ void sc_region(int r, int& z, int& roff, int& s){
  if (r < 64){ z=0; roff=0; s=5; }
  else if (r < 192){ z=1; roff=64; s=20; }
  else { z=2; roff=192; s=50; }
}

__global__ __launch_bounds__(256) void k_ln_sc(
    const float* __restrict__ h, const float* __restrict__ gb, const float* __restrict__ bb,
    unsigned short* __restrict__ dst)
{
  __shared__ float r1[4], r2[4];
  int r = blockIdx.x, tid = threadIdx.x;
  int z, roff, s; sc_region(r, z, roff, s);
  int local = r - roff;
  if (local >= 4*s) return;
  int b = local / s, t = local % s;
  float v = h[(b*1024 + (1024 - s) + t)*256 + tid];
  const float* g = gb + z*256; const float* be = bb + z*256;
  float s1 = v, s2 = v*v;
  #pragma unroll
  for (int o = 32; o > 0; o >>= 1){ s1 += __shfl_down(s1,o,64); s2 += __shfl_down(s2,o,64); }
  if ((tid & 63) == 0){ r1[tid>>6] = s1; r2[tid>>6] = s2; }
  __syncthreads();
  float S1 = r1[0]+r1[1]+r1[2]+r1[3];
  float S2 = r2[0]+r2[1]+r2[2]+r2[3];
  float m = S1*(1.f/256.f);
  float var = S2*(1.f/256.f) - m*m;
  dst[r*256 + tid] = f2bf((v - m)*rsqrtf(var + 1e-5f)*g[tid] + be[tid]);
}

// ---------------- MFMA GEMM: C = A(M,K)bf16 @ W(N,K)bf16^T, fp32 acc -------
template<int MODE, int SCB>
__global__ __launch_bounds__(256) void k_mm64(
    const unsigned short* __restrict__ A, const unsigned short* __restrict__ Wb,
    float* __restrict__ C,
    const float* __restrict__ resid,
    float* __restrict__ pool_out,
    int M, int N, int K, int wstr)
{
  int tid = threadIdx.x;
  int wave = tid >> 6, lane = tid & 63;
  int mh = wave & 1, nh = wave >> 1;
  int m0 = blockIdx.y*64 + mh*32;
  int n0 = blockIdx.x*64 + nh*32;
  int z = 0, roff = 0, sc = 0;
  const unsigned short* W = Wb;
  if (SCB){ sc_region(blockIdx.y*64, z, roff, sc); W += z*wstr; }
  int lrow = lane & 15, kc = lane >> 4;
  f32x4 acc[2][2] = {{{0.f,0.f,0.f,0.f},{0.f,0.f,0.f,0.f}},{{0.f,0.f,0.f,0.f},{0.f,0.f,0.f,0.f}}};
  for (int k0 = 0; k0 < K; k0 += 32){
    short8v a[2], b[2];
    #pragma unroll
    for (int mi = 0; mi < 2; mi++){
      int r = m0 + mi*16 + lrow; r = min(r, M-1);
      a[mi] = *(const short8v*)(A + r*K + k0 + kc*8);
    }
    #pragma unroll
    for (int ni = 0; ni < 2; ni++){
      int c = n0 + ni*16 + lrow;
      b[ni] = *(const short8v*)(W + c*K + k0 + kc*8);
    }
    #pragma unroll
    for (int mi = 0; mi < 2; mi++)
      #pragma unroll
      for (int ni = 0; ni < 2; ni++)
        acc[mi][ni] = __builtin_amdgcn_mfma_f32_16x16x32_bf16(a[mi], b[ni], acc[mi][ni], 0, 0, 0);
  }
  int rb = kc*4;
  #pragma unroll
  for (int mi = 0; mi < 2; mi++){
    #pragma unroll
    for (int rr = 0; rr < 4; rr++){
      int grow = m0 + mi*16 + rb + rr;
      if (grow >= M) continue;
      #pragma unroll
      for (int ni = 0; ni < 2; ni++){
        int gcol = n0 + ni*16 + lrow;
        float v = acc[mi][ni][rr];
        if (MODE == 0){
          C[grow*N + gcol] = v;
        } else if (MODE == 1){
          C[grow*N + gcol] = resid[grow*256 + gcol] + v;
        } else {
          int local = grow - roff;
          if (local < 4*sc){
            int bb2 = local / sc, t = local % sc;
            float rv = resid[(bb2*1024 + (1024 - sc) + t)*256 + gcol] + v;
            atomicAdd(&pool_out[bb2*768 + z*256 + gcol], rv*(1.f/(float)sc));
          }
        }
      }
    }
  }
}

// ---- split-K wide xp GEMM + fused dt --------------------------------------
// one block per 16 rows; 4 waves each take a K-quarter; LDS reduce; then dt.
// NT=3: main (NC=48, xd[.][48]); NT=2: scale (NC=32), SCB=1 selects weights.
template<int NT, int SCB>
__global__ __launch_bounds__(256) void k_xpdt(
    const unsigned short* __restrict__ A, const unsigned short* __restrict__ Wb,
    float* __restrict__ xdout,
    const float* __restrict__ dtwb, const float* __restrict__ dtbb,
    float* __restrict__ dtout, int M)
{
  const int K = 512;
  const int NC = NT*16;
  __shared__ float pacc[4][16][NC];
  __shared__ float sxd[16][16];
  int tid = threadIdx.x;
  int wave = tid >> 6, lane = tid & 63;
  int bm0 = blockIdx.x*16;
  const unsigned short* W = Wb;
  const float* dtw = dtwb;
  const float* dtb = dtbb;
  if (SCB){
    int z, roff, s; sc_region(bm0, z, roff, s);
    W += z*(NC*K); dtw += z*8192; dtb += z*512;
  }
  int lrow = lane & 15, kc = lane >> 4;
  int kbase = wave*128;
  f32x4 acc[NT];
  #pragma unroll
  for (int ni = 0; ni < NT; ni++) acc[ni] = (f32x4){0.f,0.f,0.f,0.f};
  #pragma unroll
  for (int k0 = 0; k0 < 128; k0 += 32){
    short8v a = *(const short8v*)(A + (bm0 + lrow)*K + kbase + k0 + kc*8);
    #pragma unroll
    for (int ni = 0; ni < NT; ni++){
      short8v b = *(const short8v*)(W + (ni*16 + lrow)*K + kbase + k0 + kc*8);
      acc[ni] = __builtin_amdgcn_mfma_f32_16x16x32_bf16(a, b, acc[ni], 0, 0, 0);
    }
  }
  int rb = kc*4;
  #pragma unroll
  for (int rr = 0; rr < 4; rr++)
    #pragma unroll
    for (int ni = 0; ni < NT; ni++)
      pacc[wave][rb + rr][ni*16 + lrow] = acc[ni][rr];
  __syncthreads();
  for (int e = tid; e < 16*NC; e += 256){
    int r = e / NC, c = e % NC;
    float v = pacc[0][r][c] + pacc[1][r][c] + pacc[2][r][c] + pacc[3][r][c];
    xdout[(bm0 + r)*NC + c] = v;
    if (c < 16) sxd[r][c] = v;
  }
  __syncthreads();
  // dt: thread -> d0 = tid, d1 = tid+256, over the block's 16 rows
  int d0 = tid, d1 = tid + 256;
  float w0[16], w1[16];
  #pragma unroll
  for (int j = 0; j < 16; j++){ w0[j] = dtw[d0*16 + j]; w1[j] = dtw[d1*16 + j]; }
  float b0 = dtb[d0], b1 = dtb[d1];
  #pragma unroll
  for (int r = 0; r < 16; r++){
    float a0 = b0, a1 = b1;
    #pragma unroll
    for (int j = 0; j < 16; j++){
      float xv = sxd[r][j];
      a0 = fmaf(xv, w0[j], a0);
      a1 = fmaf(xv, w1[j], a1);
    }
    dtout[(bm0 + r)*512 + d0] = softplusf_(a0);
    dtout[(bm0 + r)*512 + d1] = softplusf_(a1);
  }
}

// ---------------- depthwise causal conv (DC=4) + SiLU ----------------------
__global__ __launch_bounds__(256) void k_conv(
    const float* __restrict__ uz, const float* __restrict__ cw, const float* __restrict__ cb,
    float* __restrict__ uc, unsigned short* __restrict__ ucb)
{
  int row = blockIdx.x;
  int t = row & 1023;
  int tid = threadIdx.x;
  for (int d = tid; d < 512; d += 256){
    float acc = cb[d];
    const float* w = cw + d*4;
    #pragma unroll
    for (int k = 0; k < 4; k++){
      int ts = t - 3 + k;
      if (ts >= 0) acc += uz[(row - (3-k))*1024 + d]*w[k];
    }
    float s = acc/(1.f + expf(-acc));
    uc[row*512 + d] = s;
    ucb[row*512 + d] = f2bf(s);
  }
}

__global__ __launch_bounds__(256) void k_conv_sc(
    const float* __restrict__ uz, const float* __restrict__ cwb, const float* __restrict__ cbb,
    float* __restrict__ uc, unsigned short* __restrict__ ucb)
{
  int row = blockIdx.x;
  int z, roff, s; sc_region(row, z, roff, s);
  int local = row - roff;
  if (local >= 4*s) return;
  int t = local % s;
  const float* cw = cwb + z*2048;
  const float* cb = cbb + z*512;
  int tid = threadIdx.x;
  for (int d = tid; d < 512; d += 256){
    float acc = cb[d];
    const float* w = cw + d*4;
    #pragma unroll
    for (int k = 0; k < 4; k++){
      int ts = t - 3 + k;
      if (ts >= 0) acc += uz[(row - (3-k))*1024 + d]*w[k];
    }
    float sv = acc/(1.f + expf(-acc));
    uc[row*512 + d] = sv;
    ucb[row*512 + d] = f2bf(sv);
  }
}

// ============ chunked scan: p1 (serial local) + p2 + parallel correction ===
__global__ __launch_bounds__(64) void k_scan_p1y(
    const float* __restrict__ dt, const float* __restrict__ uc,
    const float* __restrict__ xd, const float* __restrict__ Alog,
    float* __restrict__ hend, float* __restrict__ sdtb,
    float* __restrict__ yloc, float* __restrict__ Scum)
{
  const int CL = 64, NCH = 16;
  __shared__ float sdt[64][64], suc[64][64];
  __shared__ float sBC[64][32];
  int tid = threadIdx.x;
  int dblk = blockIdx.x;
  int d = dblk*64 + tid;
  int b = blockIdx.y, ch = blockIdx.z;
  int t0 = ch*CL;
  float A[16];
  #pragma unroll
  for (int n = 0; n < 16; n++) A[n] = -__expf(Alog[d*16 + n]);
  for (int e = tid; e < CL*16; e += 64){
    int t = e >> 4, q = (e & 15)*4;
    long off = (long)(b*1024 + t0 + t)*512 + dblk*64 + q;
    *(float4*)&sdt[t][q] = *(const float4*)(dt + off);
    *(float4*)&suc[t][q] = *(const float4*)(uc + off);
  }
  for (int e = tid; e < CL*8; e += 64){
    int t = e >> 3, q = (e & 7)*4;
    *(float4*)&sBC[t][q] = *(const float4*)(xd + (long)(b*1024 + t0 + t)*48 + 16 + q);
  }
  __syncthreads();
  float h[16];
  #pragma unroll
  for (int n = 0; n < 16; n++) h[n] = 0.f;
  float Ss = 0.f;
  #pragma unroll 2
  for (int t = 0; t < CL; t++){
    float dtv = sdt[t][tid];
    float uv  = suc[t][tid];
    Ss += dtv;
    float du = dtv*uv;
    float y = 0.f;
    #pragma unroll
    for (int n = 0; n < 16; n++){
      h[n] = fmaf(__expf(dtv*A[n]), h[n], du*sBC[t][n]);
      y = fmaf(h[n], sBC[t][16+n], y);
    }
    long row = (long)(b*1024 + t0 + t);
    yloc[row*512 + d] = y;
    Scum[row*512 + d] = Ss;
  }
  int base = ((b*NCH + ch)*512 + d)*16;
  #pragma unroll
  for (int q = 0; q < 4; q++)
    *(float4*)(hend + base + q*4) = make_float4(h[q*4], h[q*4+1], h[q*4+2], h[q*4+3]);
  sdtb[(b*NCH + ch)*512 + d] = Ss;
}

__global__ __launch_bounds__(256) void k_scomb(
    const float* __restrict__ hend, const float* __restrict__ sdtb,
    const float* __restrict__ Alog, float* __restrict__ hstart,
    float* __restrict__ Aneg)
{
  const int NCH = 16;
  int idx = blockIdx.x*256 + threadIdx.x;
  int low = idx & 8191;
  int d = (idx >> 4) & 511, b = idx >> 13;
  float A = -__expf(Alog[low]);
  if (b == 0) Aneg[low] = A;
  float hs = 0.f;
  hstart[(b*NCH)*8192 + low] = 0.f;
  for (int c = 0; c < NCH-1; c++){
    float S  = sdtb[(b*NCH + c)*512 + d];
    float he = hend[(b*NCH + c)*8192 + low];
    hs = fmaf(__expf(A*S), hs, he);
    hstart[(b*NCH + c + 1)*8192 + low] = hs;
  }
}

__global__ __launch_bounds__(256) void k_corr(
    const float* __restrict__ yloc, const float* __restrict__ Scum,
    const float* __restrict__ hstart, const float* __restrict__ Aneg,
    const float* __restrict__ xd, const float* __restrict__ uc,
    const float* __restrict__ uz, const float* __restrict__ Dp,
    unsigned short* __restrict__ yg)
{
  __shared__ float sC[16];
  int row = blockIdx.x, tid = threadIdx.x;
  int b = row >> 10, t = row & 1023, ch = t >> 6;
  if (tid < 16) sC[tid] = xd[row*48 + 32 + tid];
  __syncthreads();
  #pragma unroll
  for (int rep = 0; rep < 2; rep++){
    int d = tid + rep*256;
    float Ss = Scum[row*512 + d];
    float y  = yloc[row*512 + d];
    const float* hs = hstart + ((b*16 + ch)*512 + d)*16;
    const float* An = Aneg + d*16;
    #pragma unroll
    for (int n = 0; n < 16; n++)
      y = fmaf(__expf(An[n]*Ss)*hs[n], sC[n], y);
    float uv = uc[row*512 + d];
    y = fmaf(uv, Dp[d], y);
    float zv = uz[row*1024 + 512 + d];
    yg[row*512 + d] = f2bf(y*(zv/(1.f + __expf(-zv))));
  }
}

// ---------------- scale scan (DS=8, z-batched, single chunk) ---------------
__global__ __launch_bounds__(64) void k_scan_sc(
    const float* __restrict__ dt, const float* __restrict__ uc,
    const float* __restrict__ uz, const float* __restrict__ xd,
    const float* __restrict__ Alogb, const float* __restrict__ Dpb,
    unsigned short* __restrict__ yg)
{
  __shared__ float sdt[52][64], suc[52][64], sz[52][64];
  __shared__ float sBC[52][16];
  int tid = threadIdx.x;
  int dblk = blockIdx.x;
  int d = dblk*64 + tid;
  int b = blockIdx.y, z = blockIdx.z;
  int s = (z==0) ? 5 : (z==1) ? 20 : 50;
  int roff = (z==0) ? 0 : (z==1) ? 64 : 192;
  const float* Alog = Alogb + z*4096;
  const float* Dp   = Dpb + z*512;
  float A[8];
  #pragma unroll
  for (int n = 0; n < 8; n++) A[n] = -__expf(Alog[d*8 + n]);
  float Dv = Dp[d];
  for (int e = tid; e < s*16; e += 64){
    int t = e >> 4, q = (e & 15)*4;
    long row = (long)(roff + b*s + t);
    *(float4*)&sdt[t][q] = *(const float4*)(dt + row*512 + dblk*64 + q);
    *(float4*)&suc[t][q] = *(const float4*)(uc + row*512 + dblk*64 + q);
    *(float4*)&sz[t][q]  = *(const float4*)(uz + row*1024 + 512 + dblk*64 + q);
  }
  for (int e = tid; e < s*4; e += 64){
    int t = e >> 2, q = (e & 3)*4;
    long row = (long)(roff + b*s + t);
    *(float4*)&sBC[t][q] = *(const float4*)(xd + row*32 + 16 + q);
  }
  __syncthreads();
  float h[8];
  #pragma unroll
  for (int n = 0; n < 8; n++) h[n] = 0.f;
  for (int t = 0; t < s; t++){
    float dtv = sdt[t][tid];
    float uv  = suc[t][tid];
    float zv  = sz[t][tid];
    float du = dtv*uv;
    float y = 0.f;
    #pragma unroll
    for (int n = 0; n < 8; n++){
      h[n] = fmaf(__expf(dtv*A[n]), h[n], du*sBC[t][n]);
      y = fmaf(h[n], sBC[t][8+n], y);
    }
    y = fmaf(uv, Dv, y);
    float gate = zv/(1.f + __expf(-zv));
    yg[(long)(roff + b*s + t)*512 + d] = f2bf(y*gate);
  }
}

__global__ void k_zero(float* p, int n){
  int i = blockIdx.x*256 + threadIdx.x;
  if (i < n) p[i] = 0.f;
}

// ================== tail kernels (wide, multi-kernel) ======================
template<int M, int ACT, int RES>
__global__ __launch_bounds__(256) void k_tw(
    const float* __restrict__ A, const float* __restrict__ W,
    const float* __restrict__ bias, float* __restrict__ out,
    const float* __restrict__ resid, int N, int K, int ostride, int ocoff)
{
  extern __shared__ float sx[];
  int tid = threadIdx.x;
  for (int e = tid*4; e < M*K; e += 1024)
    *(float4*)&sx[e] = *(const float4*)(A + e);
  __syncthreads();
  int wave = tid >> 6, lane = tid & 63;
  int c = blockIdx.x*4 + wave;
  if (c >= N) return;
  float acc[M];
  #pragma unroll
  for (int r = 0; r < M; r++) acc[r] = 0.f;
  for (int k = lane*4; k < K; k += 256){
    float4 w4 = *(const float4*)(W + c*K + k);
    #pragma unroll
    for (int r = 0; r < M; r++){
      float4 x4 = *(float4*)&sx[r*K + k];
      acc[r] = fmaf(x4.x,w4.x,fmaf(x4.y,w4.y,fmaf(x4.z,w4.z,fmaf(x4.w,w4.w,acc[r]))));
    }
  }
  #pragma unroll
  for (int r = 0; r < M; r++){
    #pragma unroll
    for (int o = 32; o > 0; o >>= 1) acc[r] += __shfl_down(acc[r], o, 64);
  }
  if (lane == 0){
    float bv = bias[c];
    #pragma unroll
    for (int r = 0; r < M; r++){
      float v = acc[r] + bv;
      if (ACT == 1) v = geluf(v);
      if (RES == 1) v += resid[r*256 + c];
      out[r*ostride + ocoff + c] = v;
    }
  }
}

__global__ __launch_bounds__(256) void k_t_ln(
    const float* __restrict__ src, const float* __restrict__ g, const float* __restrict__ b,
    float* __restrict__ dst)
{
  __shared__ float r1[4], r2[4];
  int r = blockIdx.x, tid = threadIdx.x;
  float v = src[r*256 + tid];
  float s1 = v, s2 = v*v;
  #pragma unroll
  for (int o = 32; o > 0; o >>= 1){ s1 += __shfl_down(s1,o,64); s2 += __shfl_down(s2,o,64); }
  if ((tid & 63) == 0){ r1[tid>>6] = s1; r2[tid>>6] = s2; }
  __syncthreads();
  float S1 = r1[0]+r1[1]+r1[2]+r1[3];
  float S2 = r2[0]+r2[1]+r2[2]+r2[3];
  float m = S1*(1.f/256.f);
  float var = S2*(1.f/256.f) - m*m;
  dst[r*256 + tid] = (v - m)*rsqrtf(var + 1e-5f)*g[tid] + b[tid];
}

__global__ __launch_bounds__(256) void k_t_att(
    const float* __restrict__ qkv, float* __restrict__ ov)
{
  __shared__ float att[36];
  int b = blockIdx.x, tid = threadIdx.x;
  if (tid < 36){
    int hh = tid/9, r = (tid%9)/3, c = tid%3;
    float s = 0.f;
    const float* qp = qkv + (b*3 + r)*768 + hh*64;
    const float* kp = qkv + (b*3 + c)*768 + 256 + hh*64;
    for (int k = 0; k < 64; k++) s += qp[k]*kp[k];
    att[hh*9 + r*3 + c] = s*0.125f;
  }
  __syncthreads();
  if (tid < 12){
    int hh = tid/3, r = tid%3;
    float a0 = att[hh*9+r*3+0], a1 = att[hh*9+r*3+1], a2 = att[hh*9+r*3+2];
    float m = fmaxf(a0, fmaxf(a1, a2));
    float e0 = expf(a0-m), e1 = expf(a1-m), e2 = expf(a2-m);
    float s = e0+e1+e2;
    att[hh*9+r*3+0] = e0/s; att[hh*9+r*3+1] = e1/s; att[hh*9+r*3+2] = e2/s;
  }
  __syncthreads();
  for (int e = tid; e < 768; e += 256){
    int p = e >> 8, i = e & 255, hh = i >> 6;
    ov[(b*3 + p)*256 + i] = att[hh*9+p*3+0]*qkv[(b*3+0)*768+512+i]
                          + att[hh*9+p*3+1]*qkv[(b*3+1)*768+512+i]
                          + att[hh*9+p*3+2]*qkv[(b*3+2)*768+512+i];
  }
}

__global__ __launch_bounds__(256) void k_t_final(
    const float* __restrict__ fusedv, const float* __restrict__ s2f, float* __restrict__ finalv)
{
  int b = blockIdx.x, c = threadIdx.x;
  finalv[b*256 + c] = fusedv[b*256 + c] +
    (s2f[(b*3+0)*256 + c] + s2f[(b*3+1)*256 + c] + s2f[(b*3+2)*256 + c])*(1.f/3.f);
}

__global__ __launch_bounds__(64) void k_t_fin(
    const float* __restrict__ evraw, const float* __restrict__ ttraw, float* __restrict__ out)
{
  __shared__ float ev[7];
  __shared__ float S;
  int b = blockIdx.x, tid = threadIdx.x;
  if (tid < 7) ev[tid] = softplusf_(evraw[b*7 + tid]);
  __syncthreads();
  if (tid == 0){
    float s = 0.f;
    for (int j = 0; j < 7; j++) s += ev[j] + 1.f;
    S = s;
  }
  __syncthreads();
  float* ob = out + b*162;
  if (tid < 7){
    float al = ev[tid] + 1.f;
    ob[tid] = al / S;
    ob[7 + tid] = ev[tid];
    ob[14 + tid] = al;
  }
  if (tid == 0) ob[21] = 7.f / S;
  if (tid < 6){
    ob[22 + tid] = softplusf_(ttraw[b*12 + tid]);
    ob[28 + tid] = expf(0.5f*ttraw[b*12 + 6 + tid]);
  }
}

// ---------------------------------------------------------------------------
extern "C" void kernel_launch(void* const* d_in, const int* in_sizes, int n_in,
                              void* d_out, int out_size, void* d_ws, size_t ws_size,
                              hipStream_t stream)
{
  const float* x         = (const float*)d_in[0];
  const float* in_w      = (const float*)d_in[1];
  const float* in_b      = (const float*)d_in[2];
  const float* in_ln_g   = (const float*)d_in[3];
  const float* in_ln_b   = (const float*)d_in[4];
  const float* mb_ln_g   = (const float*)d_in[5];
  const float* mb_ln_b   = (const float*)d_in[6];
  const float* mb_in_w   = (const float*)d_in[7];
  const float* mb_conv_w = (const float*)d_in[8];
  const float* mb_conv_b = (const float*)d_in[9];
  const float* mb_xp_w   = (const float*)d_in[10];
  const float* mb_dt_w   = (const float*)d_in[11];
  const float* mb_dt_b   = (const float*)d_in[12];
  const float* mb_Alog   = (const float*)d_in[13];
  const float* mb_D      = (const float*)d_in[14];
  const float* mb_out_w  = (const float*)d_in[15];
  const float* sc_ln_g   = (const float*)d_in[16];
  const float* sc_ln_b   = (const float*)d_in[17];
  const float* sc_in_w   = (const float*)d_in[18];
  const float* sc_conv_w = (const float*)d_in[19];
  const float* sc_conv_b = (const float*)d_in[20];
  const float* sc_xp_w   = (const float*)d_in[21];
  const float* sc_dt_w   = (const float*)d_in[22];
  const float* sc_dt_b   = (const float*)d_in[23];
  const float* sc_Alog   = (const float*)d_in[24];
  const float* sc_D      = (const float*)d_in[25];
  const float* sc_out_w  = (const float*)d_in[26];
  const float* fus_qkv_w = (const float*)d_in[27];
  const float* fus_qkv_b = (const float*)d_in[28];
  const float* fus_out_w = (const float*)d_in[29];
  const float* fus_out_b = (const float*)d_in[30];
  const float* ms_out_w  = (const float*)d_in[31];
  const float* ms_out_b  = (const float*)d_in[32];
  const float* sa_ln1_g  = (const float*)d_in[33];
  const float* sa_ln1_b  = (const float*)d_in[34];
  const float* sa_ln2_g  = (const float*)d_in[35];
  const float* sa_ln2_b  = (const float*)d_in[36];
  const float* sa_qkv_w  = (const float*)d_in[37];
  const float* sa_qkv_b  = (const float*)d_in[38];
  const float* sa_out_w  = (const float*)d_in[39];
  const float* sa_out_b  = (const float*)d_in[40];
  const float* sa_ff1_w  = (const float*)d_in[41];
  const float* sa_ff1_b  = (const float*)d_in[42];
  const float* sa_ff2_w  = (const float*)d_in[43];
  const float* sa_ff2_b  = (const float*)d_in[44];
  const float* ev1_w     = (const float*)d_in[45];
  const float* ev1_b     = (const float*)d_in[46];
  const float* ev2_w     = (const float*)d_in[47];
  const float* ev2_b     = (const float*)d_in[48];
  const float* ttf1_w    = (const float*)d_in[49];
  const float* ttf1_b    = (const float*)d_in[50];
  const float* ttf2_w    = (const float*)d_in[51];
  const float* ttf2_b    = (const float*)d_in[52];
  const float* emb_w     = (const float*)d_in[53];
  const float* emb_b     = (const float*)d_in[54];

  float* ws = (float*)d_ws;
  float* h     = ws;                        // 1,048,576
  float* uz    = h    + 1048576;            // 4,194,304
  float* uc    = uz   + 4194304;            // 2,097,152
  float* dtb_  = uc   + 2097152;            // 2,097,152
  float* xd    = dtb_ + 2097152;            // 196,608
  float* stack = xd   + 196608;             // 4,096
  float* hend   = stack + 4096;          // 524,288
  float* hstart = hend + 524288;         // 524,288
  float* sdtb   = hstart + 524288;       // 32,768
  float* yloc   = sdtb + 32768;          // 2,097,152
  float* Scum   = yloc + 2097152;        // 2,097,152
  float* Aneg   = Scum + 2097152;        // 8,192
  // tail buffers
  float* qkvF   = Aneg + 8192;   // 9216
  float* ovF    = qkvF + 9216;   // 3072
  float* moF    = ovF  + 3072;   // 3072
  float* fusedv = moF  + 3072;   // 1024
  float* lnbuf  = fusedv + 1024; // 3072
  float* qkvS   = lnbuf + 3072;  // 9216
  float* ovS    = qkvS + 9216;   // 3072
  float* s2     = ovS  + 3072;   // 3072
  float* ln2r   = s2   + 3072;   // 3072
  float* hid    = ln2r + 3072;   // 12288
  float* s2f    = hid  + 12288;  // 3072
  float* finalv = s2f  + 3072;   // 1024
  float* evh    = finalv + 1024; // 1024
  float* tth    = evh  + 1024;   // 512
  float* evraw  = tth  + 512;    // 32
  float* ttraw  = evraw + 32;    // 64
  float* fp32_end = ttraw + 64;
  unsigned short* bfb = (unsigned short*)fp32_end;
  unsigned short* xnb    = bfb;                  // 1,048,576
  unsigned short* ucb    = xnb + 1048576;        // 2,097,152
  unsigned short* ygb    = ucb + 2097152;        // 2,097,152
  unsigned short* wmbin  = ygb + 2097152;        // 1,048,576
  unsigned short* wmbout = wmbin + 1048576;      // 524,288
  unsigned short* wmbxp  = wmbout + 524288;      // 98,304
  unsigned short* wscin  = wmbxp + 98304;        // 786,432
  unsigned short* wscout = wscin + 786432;       // 393,216
  unsigned short* wscxp  = wscout + 393216;      // 49,152

  k_f2b_all<<<2832, 256, 0, stream>>>(mb_in_w, wmbin, mb_out_w, wmbout, mb_xp_w, wmbxp,
                                      sc_in_w, wscin, sc_out_w, wscout, sc_xp_w, wscxp);

  k_inproj<<<4096, 256, 0, stream>>>(x, in_w, in_b, in_ln_g, in_ln_b, h);

  for (int l = 0; l < 4; l++){
    const float* Al = mb_Alog + l*8192;
    k_ln<<<4096, 256, 0, stream>>>(h, mb_ln_g + l*256, mb_ln_b + l*256, xnb);
    {
      dim3 g(16, 64);
      k_mm64<0,0><<<g, 256, 0, stream>>>(xnb, wmbin + l*262144, uz,
                                         nullptr, nullptr, 4096, 1024, 256, 0);
    }
    k_conv<<<4096, 256, 0, stream>>>(uz, mb_conv_w + l*2048, mb_conv_b + l*512, uc, ucb);
    k_xpdt<3,0><<<256, 256, 0, stream>>>(ucb, wmbxp + l*24576, xd,
                                         mb_dt_w + l*8192, mb_dt_b + l*512, dtb_, 4096);
    {
      dim3 g(8, 4, 16);
      k_scan_p1y<<<g, 64, 0, stream>>>(dtb_, uc, xd, Al, hend, sdtb, yloc, Scum);
      k_scomb<<<128, 256, 0, stream>>>(hend, sdtb, Al, hstart, Aneg);
      k_corr<<<4096, 256, 0, stream>>>(yloc, Scum, hstart, Aneg, xd, uc, uz,
                                       mb_D + l*512, ygb);
    }
    {
      dim3 g(4, 64);
      k_mm64<1,0><<<g, 256, 0, stream>>>(ygb, wmbout + l*131072, h,
                                         h, nullptr, 4096, 256, 512, 0);
    }
  }

  // ---- scale mambas (batched), pooled -> stack ----
  k_zero<<<12, 256, 0, stream>>>(stack, 3072);
  k_ln_sc<<<448, 256, 0, stream>>>(h, sc_ln_g, sc_ln_b, xnb);
  {
    dim3 g(16, 7);
    k_mm64<0,1><<<g, 256, 0, stream>>>(xnb, wscin, uz, nullptr, nullptr,
                                       448, 1024, 256, 262144);
  }
  k_conv_sc<<<448, 256, 0, stream>>>(uz, sc_conv_w, sc_conv_b, uc, ucb);
  k_xpdt<2,1><<<28, 256, 0, stream>>>(ucb, wscxp, xd, sc_dt_w, sc_dt_b, dtb_, 448);
  {
    dim3 g(8, 4, 3);
    k_scan_sc<<<g, 64, 0, stream>>>(dtb_, uc, uz, xd, sc_Alog, sc_D, ygb);
  }
  {
    dim3 g(4, 7);
    k_mm64<2,1><<<g, 256, 0, stream>>>(ygb, wscout, nullptr, h, stack,
                                       448, 256, 512, 131072);
  }

  // ---- tail (wide multi-kernel) ----
  float* dout = (float*)d_out;
  k_tw<12,0,0><<<192, 256, 12*256*4, stream>>>(stack, fus_qkv_w, fus_qkv_b, qkvF, nullptr, 768, 256, 768, 0);
  k_t_att<<<4, 256, 0, stream>>>(qkvF, ovF);
  k_tw<12,0,0><<<64, 256, 12*256*4, stream>>>(ovF, fus_out_w, fus_out_b, moF, nullptr, 256, 256, 256, 0);
  k_tw<4,0,0><<<64, 256, 4*768*4, stream>>>(moF, ms_out_w, ms_out_b, fusedv, nullptr, 256, 768, 256, 0);
  k_t_ln<<<12, 256, 0, stream>>>(stack, sa_ln1_g, sa_ln1_b, lnbuf);
  k_tw<12,0,0><<<192, 256, 12*256*4, stream>>>(lnbuf, sa_qkv_w, sa_qkv_b, qkvS, nullptr, 768, 256, 768, 0);
  k_t_att<<<4, 256, 0, stream>>>(qkvS, ovS);
  k_tw<12,0,1><<<64, 256, 12*256*4, stream>>>(ovS, sa_out_w, sa_out_b, s2, stack, 256, 256, 256, 0);
  k_t_ln<<<12, 256, 0, stream>>>(s2, sa_ln2_g, sa_ln2_b, ln2r);
  k_tw<12,1,0><<<256, 256, 12*256*4, stream>>>(ln2r, sa_ff1_w, sa_ff1_b, hid, nullptr, 1024, 256, 1024, 0);
  k_tw<12,0,1><<<64, 256, 12*1024*4, stream>>>(hid, sa_ff2_w, sa_ff2_b, s2f, s2, 256, 1024, 256, 0);
  k_t_final<<<4, 256, 0, stream>>>(fusedv, s2f, finalv);
  k_tw<4,1,0><<<64, 256, 4*256*4, stream>>>(finalv, ev1_w, ev1_b, evh, nullptr, 256, 256, 256, 0);
  k_tw<4,0,0><<<2, 256, 4*256*4, stream>>>(evh, ev2_w, ev2_b, evraw, nullptr, 7, 256, 7, 0);
  k_tw<4,1,0><<<32, 256, 4*256*4, stream>>>(finalv, ttf1_w, ttf1_b, tth, nullptr, 128, 256, 128, 0);
  k_tw<4,0,0><<<3, 256, 4*128*4, stream>>>(tth, ttf2_w, ttf2_b, ttraw, nullptr, 12, 128, 12, 0);
  k_tw<4,0,0><<<32, 256, 4*256*4, stream>>>(finalv, emb_w, emb_b, dout, nullptr, 128, 256, 162, 34);
  k_t_fin<<<4, 64, 0, stream>>>(evraw, ttraw, dout);
}